// Round 15
// baseline (393.286 us; speedup 1.0000x reference)
//
#include <hip/hip_runtime.h>
#include <hip/hip_bf16.h>

// Problem constants (match reference)
constexpr int N   = 20000;   // vertices
constexpr int T   = 32;      // temporal depth
constexpr int E   = 640000;  // edges
constexpr int C   = 10;      // conv out channels
constexpr int K   = 5;       // conv kernel size
constexpr int SB  = 16;      // stats replication banks (caps atomic fan-in/address)
constexpr int OB  = 64;      // out-partial banks
constexpr int NR  = 8;       // dst ranges (one per XCD)
constexpr int CAP = 96;      // node bucket capacity: 96 ushort = 3 lines
constexpr int RSPAN = N / NR;          // 2500 nodes per range
constexpr int PB   = 625;    // partition blocks
constexpr int PE   = 1024;   // edges per partition block (PB*PE == E)
constexpr int WCAP = 80;     // per (wave,range) LDS capacity (mean 32, 9 sigma)
constexpr int PCAP = 320;    // per (block,range) global capacity = 4*WCAP, 20 lines
constexpr int CNTW = 5008;   // cnt words, padded for 64B alignment (NOT zeroed)
// fused bin||node geometry
constexpr int BCHUNK     = (PB + 3) / 4;        // 157 bundle-chunks per range
constexpr int BIN_BLOCKS = NR * BCHUNK;         // 1256 (r = blockIdx & 7)
constexpr int NODE_BLOCKS = N * 32 / 256;       // 2500
// zeroed prefix: deg + statsA + statsB + opart + done(+pad)
constexpr int ZWORDS = N + 2 * SB * 64 + OB * 3 + 16;
// alignment audit: deg 80000B + statsA 4096 + statsB 4096 + opart 768 +
// done/pad 64 = 89024 B == 0 mod 64; cnt 20032 B -> 109056 == 0 mod 64;
// bufG 6.4MB, slot 3.84MB, msg 1.28MB all 64B-multiples -> every gather
// target buffer stays line-aligned (R13 lesson).

__device__ __forceinline__ float bf_lo(unsigned m) {
    return __uint_as_float(m << 16);
}
__device__ __forceinline__ float bf_hi(unsigned m) {
    return __uint_as_float(m & 0xffff0000u);
}

// ---------------------------------------------------------------------------
// 0) zero deg + statsA + statsB + opart + done (contiguous at ws start)
__global__ void k_zero(int* __restrict__ p) {
    int i = blockIdx.x * 256 + threadIdx.x;
    if (i < ZWORDS) p[i] = 0;
}

// ---------------------------------------------------------------------------
// 1) phase-1 radix partition + fused layer-0 column stats (R14-proven).
__global__ __launch_bounds__(256) void k_part(
    const int* __restrict__ src, const int* __restrict__ dst,
    unsigned* __restrict__ bufG, int* __restrict__ cnt,
    const float* __restrict__ x, float* __restrict__ statsA) {
    __shared__ unsigned bufL[4][NR][WCAP];
    __shared__ int cW[4][NR];
    __shared__ int base[4][NR];
    __shared__ float sred[64];
    int tid = threadIdx.x, w = tid >> 6;
    if (tid < 32) cW[tid >> 3][tid & 7] = 0;
    __syncthreads();
    int e = blockIdx.x * PE + tid * 4;
    int4 d4 = *(const int4*)(dst + e);
    int4 s4 = *(const int4*)(src + e);
    int dd[4] = {d4.x, d4.y, d4.z, d4.w};
    int ss[4] = {s4.x, s4.y, s4.z, s4.w};
#pragma unroll
    for (int k = 0; k < 4; ++k) {
        int d = dd[k];
        int r = d / RSPAN;                // magic-mul divide
        int dl = d - r * RSPAN;
        int pos = atomicAdd(&cW[w][r], 1);
        if (pos < WCAP)
            bufL[w][r][pos] = ((unsigned)dl << 15) | (unsigned)ss[k];
    }
    __syncthreads();
    if (tid < 32) {                       // thread (w,r): flush base offsets
        int ww = tid >> 3, rr = tid & 7;
        int b = 0;
        for (int u = 0; u < ww; ++u) b += min(cW[u][rr], WCAP);
        base[ww][rr] = b;
        if (ww == 3) cnt[rr * PB + blockIdx.x] = b + min(cW[3][rr], WCAP);
    }
    __syncthreads();
    int lane = tid & 63;
    for (int r = 0; r < NR; ++r) {
        int c = min(cW[w][r], WCAP);
        unsigned* dp = bufG + ((size_t)r * PB + blockIdx.x) * PCAP + base[w][r];
        for (int i = lane; i < c; i += 64) dp[i] = bufL[w][r][i];
    }
    // fused layer-0 column stats (float4; PB*256 == N*T/4 exactly)
    int gid = blockIdx.x * 256 + tid;
    int GS  = gridDim.x * 256;
    const float4* x4 = (const float4*)x;
    float s0 = 0.f, s1 = 0.f, s2 = 0.f, s3 = 0.f;
    float q0 = 0.f, q1 = 0.f, q2 = 0.f, q3 = 0.f;
    for (int i = gid; i < N * T / 4; i += GS) {
        float4 v = x4[i];
        s0 += v.x; q0 += v.x * v.x;
        s1 += v.y; q1 += v.y * v.y;
        s2 += v.z; q2 += v.z * v.z;
        s3 += v.w; q3 += v.w * v.w;
    }
    int c4 = (tid & 7) * 4;
#pragma unroll
    for (int ofs = 8; ofs < 64; ofs <<= 1) {
        s0 += __shfl_xor(s0, ofs); q0 += __shfl_xor(q0, ofs);
        s1 += __shfl_xor(s1, ofs); q1 += __shfl_xor(q1, ofs);
        s2 += __shfl_xor(s2, ofs); q2 += __shfl_xor(q2, ofs);
        s3 += __shfl_xor(s3, ofs); q3 += __shfl_xor(q3, ofs);
    }
    if (tid < 64) sred[tid] = 0.f;
    __syncthreads();
    if ((tid & 63) < 8) {
        atomicAdd(&sred[c4 + 0], s0); atomicAdd(&sred[32 + c4 + 0], q0);
        atomicAdd(&sred[c4 + 1], s1); atomicAdd(&sred[32 + c4 + 1], q1);
        atomicAdd(&sred[c4 + 2], s2); atomicAdd(&sred[32 + c4 + 2], q2);
        atomicAdd(&sred[c4 + 3], s3); atomicAdd(&sred[32 + c4 + 3], q3);
    }
    __syncthreads();
    if (tid < 64)
        atomicAdd(&statsA[(blockIdx.x & (SB - 1)) * 64 + tid], sred[tid]);
}

// ---------------------------------------------------------------------------
// 2) FUSED bin2 || node0. Blocks [0, BIN_BLOCKS) scatter packed edges into
//    node buckets (one wave per (r,b) bundle; r = blockIdx&7 keeps XCD
//    affinity). Blocks [BIN_BLOCKS, +NODE_BLOCKS) run layer-0 norm+conv+max.
//    Independent work -> co-resident overlap instead of serial dispatches.
__global__ __launch_bounds__(256) void k_binnode(
    const unsigned* __restrict__ bufG, const int* __restrict__ cnt,
    int* __restrict__ deg, unsigned short* __restrict__ slot,
    const float* __restrict__ xin, const float* __restrict__ grep,
    const float* __restrict__ Wl, const float* __restrict__ bl,
    const float* __restrict__ al, const float* __restrict__ sl,
    const float* __restrict__ shl,
    float* __restrict__ xhat, unsigned short* __restrict__ msg) {
    int tid = threadIdx.x;
    if (blockIdx.x < BIN_BLOCKS) {
        int r = blockIdx.x & (NR - 1);
        int b = (blockIdx.x >> 3) * 4 + (tid >> 6);   // bundle b in range r
        if (b >= PB) return;
        int lane = tid & 63;
        int c = cnt[r * PB + b];
        const unsigned* bp = bufG + ((size_t)r * PB + b) * PCAP;
        int lo = r * RSPAN;
        for (int i = lane; i < c; i += 64) {
            unsigned pk = bp[i];
            int d = lo + (int)(pk >> 15);
            int s = (int)(pk & 32767u);
            int p = atomicAdd(&deg[d], 1);
            if (p < CAP) slot[d * CAP + p] = (unsigned short)s;
        }
        return;
    }
    // ---- node path ----
    int gid = (blockIdx.x - BIN_BLOCKS) * 256 + tid;
    int t = gid & 31;
    int row = gid >> 5;
    if (row >= N) return;

    float Sx = 0.f, Sx2 = 0.f;
#pragma unroll
    for (int b = 0; b < SB; ++b) {
        Sx  += grep[b * 64 + t];
        Sx2 += grep[b * 64 + 32 + t];
    }
    float mu   = Sx * (1.0f / (float)N);
    float am   = al[t] * mu;
    float nrm2 = Sx2 - 2.f * am * Sx + (float)N * am * am;
    float g    = sl[t] * sqrtf((float)N) * rsqrtf(nrm2);
    float h    = shl[t] - am * g;

    float v = g * xin[row * T + t] + h;
    xhat[row * T + t] = v;
    float vm2 = __shfl(v, t - 2, 32); if (t < 2)  vm2 = 0.f;
    float vm1 = __shfl(v, t - 1, 32); if (t < 1)  vm1 = 0.f;
    float vp1 = __shfl(v, t + 1, 32); if (t > 30) vp1 = 0.f;
    float vp2 = __shfl(v, t + 2, 32); if (t > 29) vp2 = 0.f;
    float m = -3.0e38f;
#pragma unroll
    for (int c = 0; c < C; ++c) {
        float a = bl[c] + Wl[c * K + 0] * vm2 + Wl[c * K + 1] * vm1
                        + Wl[c * K + 2] * v   + Wl[c * K + 3] * vp1
                        + Wl[c * K + 4] * vp2;
        m = fmaxf(m, a);
    }
    __hip_bfloat16 mb = __float2bfloat16(m);
    msg[row * T + t] = *(unsigned short*)&mb;
}

// ---------------------------------------------------------------------------
// 3) per-node GraphNorm affine + Conv1d + channel max (layer 1, standalone).
__global__ __launch_bounds__(256) void k_node(
    const float* __restrict__ xin, const float* __restrict__ grep,
    const float* __restrict__ Wl, const float* __restrict__ bl,
    const float* __restrict__ al, const float* __restrict__ sl,
    const float* __restrict__ shl,
    float* __restrict__ xhat, unsigned short* __restrict__ msg) {
    int gid = blockIdx.x * 256 + threadIdx.x;
    int t = gid & 31;
    int row = gid >> 5;
    if (row >= N) return;

    float Sx = 0.f, Sx2 = 0.f;
#pragma unroll
    for (int b = 0; b < SB; ++b) {
        Sx  += grep[b * 64 + t];
        Sx2 += grep[b * 64 + 32 + t];
    }
    float mu   = Sx * (1.0f / (float)N);
    float am   = al[t] * mu;
    float nrm2 = Sx2 - 2.f * am * Sx + (float)N * am * am;
    float g    = sl[t] * sqrtf((float)N) * rsqrtf(nrm2);
    float h    = shl[t] - am * g;

    float v = g * xin[row * T + t] + h;
    xhat[row * T + t] = v;
    float vm2 = __shfl(v, t - 2, 32); if (t < 2)  vm2 = 0.f;
    float vm1 = __shfl(v, t - 1, 32); if (t < 1)  vm1 = 0.f;
    float vp1 = __shfl(v, t + 1, 32); if (t > 30) vp1 = 0.f;
    float vp2 = __shfl(v, t + 2, 32); if (t > 29) vp2 = 0.f;
    float m = -3.0e38f;
#pragma unroll
    for (int c = 0; c < C; ++c) {
        float a = bl[c] + Wl[c * K + 0] * vm2 + Wl[c * K + 1] * vm1
                        + Wl[c * K + 2] * v   + Wl[c * K + 3] * vp1
                        + Wl[c * K + 4] * vp2;
        m = fmaxf(m, a);
    }
    __hip_bfloat16 mb = __float2bfloat16(m);
    msg[row * T + t] = *(unsigned short*)&mb;
}

// ---------------------------------------------------------------------------
// gather core (R12-proven): one wave per node; lane = g*16 + c; group g walks
// edges stride-4, 4-deep unroll -> 16 independent 64B rows in flight; lane
// covers columns (2c,2c+1) via one uint (2x bf16). fp32 accumulate.
__device__ __forceinline__ void gather_core(
    const int* __restrict__ deg, const unsigned short* __restrict__ slot,
    const unsigned* __restrict__ msgp, const float* __restrict__ xhat,
    int n, int c, int g, float* v0out, float* v1out) {
    int dg  = deg[n];
    int cnt = dg < CAP ? dg : CAP;
    const unsigned short* sl = slot + n * CAP;
    float a0 = 0.f, a1 = 0.f;
    int i = g;
    for (; i + 12 < cnt; i += 16) {
        int s0 = sl[i], s1 = sl[i + 4], s2 = sl[i + 8], s3 = sl[i + 12];
        unsigned m0 = msgp[s0 * 16 + c];
        unsigned m1 = msgp[s1 * 16 + c];
        unsigned m2 = msgp[s2 * 16 + c];
        unsigned m3 = msgp[s3 * 16 + c];
        a0 += bf_lo(m0); a1 += bf_hi(m0);
        a0 += bf_lo(m1); a1 += bf_hi(m1);
        a0 += bf_lo(m2); a1 += bf_hi(m2);
        a0 += bf_lo(m3); a1 += bf_hi(m3);
    }
    for (; i < cnt; i += 4) {
        unsigned m = msgp[(int)sl[i] * 16 + c];
        a0 += bf_lo(m); a1 += bf_hi(m);
    }
    a0 += __shfl_xor(a0, 16); a0 += __shfl_xor(a0, 32);
    a1 += __shfl_xor(a1, 16); a1 += __shfl_xor(a1, 32);
    float r = 1.0f / fmaxf((float)dg, 1.0f);
    float2 xh = ((const float2*)(xhat + n * T))[c];
    *v0out = fmaxf(0.5f * (xh.x + a0 * r), 0.f);
    *v1out = fmaxf(0.5f * (xh.y + a1 * r), 0.f);
}

// ---------------------------------------------------------------------------
// 4a) gather layer-0: epilogue -> x1 + banked next-layer stats.
__global__ __launch_bounds__(256) void k_gather0(
    const int* __restrict__ deg, const unsigned short* __restrict__ slot,
    const unsigned* __restrict__ msgp, const float* __restrict__ xhat,
    float* __restrict__ xout, float* __restrict__ statsB) {
    __shared__ float sred[64];
    int tid  = threadIdx.x;
    int gid  = blockIdx.x * 256 + tid;
    int lane = tid & 63;
    int g = lane >> 4, c = lane & 15;
    int n = gid >> 6;

    float v0 = 0.f, v1 = 0.f;
    bool valid = (n < N);
    if (valid) {
        gather_core(deg, slot, msgp, xhat, n, c, g, &v0, &v1);
        if (g == 0) {
            float2 w; w.x = v0; w.y = v1;
            ((float2*)(xout + n * T))[c] = w;
        }
    }
    if (tid < 64) sred[tid] = 0.f;
    __syncthreads();
    if (valid && g == 0) {
        atomicAdd(&sred[2 * c],          v0);
        atomicAdd(&sred[2 * c + 1],      v1);
        atomicAdd(&sred[32 + 2 * c],     v0 * v0);
        atomicAdd(&sred[32 + 2 * c + 1], v1 * v1);
    }
    __syncthreads();
    if (tid < 64)
        atomicAdd(&statsB[(blockIdx.x & (SB - 1)) * 64 + tid], sred[tid]);
}

// ---------------------------------------------------------------------------
// 4b) gather layer-1 + fused final output (last-block pattern).
__global__ __launch_bounds__(256) void k_gather1(
    const int* __restrict__ deg, const unsigned short* __restrict__ slot,
    const unsigned* __restrict__ msgp, const float* __restrict__ xhat,
    const float* __restrict__ Wout, float* __restrict__ opart,
    unsigned* __restrict__ done, const float* __restrict__ bout,
    float* __restrict__ out) {
    __shared__ float sred[3];
    __shared__ unsigned ticket;
    int tid  = threadIdx.x;
    int gid  = blockIdx.x * 256 + tid;
    int lane = tid & 63;
    int g = lane >> 4, c = lane & 15;
    int n = gid >> 6;

    float v0 = 0.f, v1 = 0.f;
    bool valid = (n < N);
    if (valid) gather_core(deg, slot, msgp, xhat, n, c, g, &v0, &v1);

    float s = v0 + v1;
    s += __shfl_xor(s, 1); s += __shfl_xor(s, 2);
    s += __shfl_xor(s, 4); s += __shfl_xor(s, 8);
    float pa0 = 0.f, pa1 = 0.f, pa2 = 0.f;
    if (valid && lane == 0) {
        pa0 = Wout[n] * s;
        pa1 = Wout[N + n] * s;
        pa2 = Wout[2 * N + n] * s;
    }
    if (tid < 3) sred[tid] = 0.f;
    __syncthreads();
    if (lane == 0) {
        atomicAdd(&sred[0], pa0);
        atomicAdd(&sred[1], pa1);
        atomicAdd(&sred[2], pa2);
    }
    __syncthreads();
    if (tid < 3)
        atomicAdd(&opart[(blockIdx.x & (OB - 1)) * 3 + tid], sred[tid]);
    // ---- last block folds the banks into the output ----
    __threadfence();                       // make this block's adds visible
    __syncthreads();
    if (tid == 0) ticket = atomicAdd(done, 1u);
    __syncthreads();
    if (ticket == (unsigned)(gridDim.x - 1) && tid < 3) {
        float acc = bout[tid];
        for (int b = 0; b < OB; ++b)
            acc += atomicAdd(&opart[b * 3 + tid], 0.0f);   // coherent L2 read
        out[tid] = acc;
    }
}

// ---------------------------------------------------------------------------
extern "C" void kernel_launch(void* const* d_in, const int* in_sizes, int n_in,
                              void* d_out, int out_size, void* d_ws, size_t ws_size,
                              hipStream_t stream) {
    const float* x     = (const float*)d_in[0];
    const float* convW = (const float*)d_in[1];
    const float* convb = (const float*)d_in[2];
    const float* alpha = (const float*)d_in[3];
    const float* scale = (const float*)d_in[4];
    const float* shift = (const float*)d_in[5];
    const float* Wout  = (const float*)d_in[6];
    const float* bout  = (const float*)d_in[7];
    const int*   ei    = (const int*)d_in[8];
    const int* src = ei;          // edge_index[0]
    const int* dst = ei + E;      // edge_index[1]

    // workspace (64B-aligned throughout; see audit comment at top)
    int*            deg    = (int*)d_ws;                  // N (bucket cursor)
    float*          statsA = (float*)(deg + N);           // SB*64
    float*          statsB = statsA + SB * 64;            // SB*64
    float*          opart  = statsB + SB * 64;            // OB*3
    unsigned*       done   = (unsigned*)(opart + OB * 3); // 1 (+15 pad)
    int*            cnt    = (int*)(done + 16);           // CNTW (not zeroed)
    unsigned*       bufG   = (unsigned*)(cnt + CNTW);     // NR*PB*PCAP
    unsigned short* slot   = (unsigned short*)(bufG + (size_t)NR * PB * PCAP);
    unsigned short* msg    = slot + (size_t)N * CAP;      // N*T (bf16 bits)
    float*          xhat   = (float*)(msg + (size_t)N * T);
    float*          x1     = xhat + N * T;
    float*          out    = (float*)d_out;

    k_zero<<<(ZWORDS + 255) / 256, 256, 0, stream>>>(deg);

    k_part<<<PB, 256, 0, stream>>>(src, dst, bufG, cnt, x, statsA);

    k_binnode<<<BIN_BLOCKS + NODE_BLOCKS, 256, 0, stream>>>(
        bufG, cnt, deg, slot,
        x, statsA, convW, convb, alpha, scale, shift, xhat, msg);

    k_gather0<<<(N * 64 + 255) / 256, 256, 0, stream>>>(
        deg, slot, (const unsigned*)msg, xhat, x1, statsB);

    k_node<<<NODE_BLOCKS, 256, 0, stream>>>(
        x1, statsB, convW + C * K, convb + C,
        alpha + T, scale + T, shift + T, xhat, msg);

    k_gather1<<<(N * 64 + 255) / 256, 256, 0, stream>>>(
        deg, slot, (const unsigned*)msg, xhat, Wout, opart, done, bout, out);
}

// Round 16
// 92.127 us; speedup vs baseline: 4.2690x; 4.2690x over previous
//
#include <hip/hip_runtime.h>
#include <hip/hip_bf16.h>

// Problem constants (match reference)
constexpr int N   = 20000;   // vertices
constexpr int T   = 32;      // temporal depth
constexpr int E   = 640000;  // edges
constexpr int C   = 10;      // conv out channels
constexpr int K   = 5;       // conv kernel size
constexpr int SB  = 16;      // stats replication banks (caps atomic fan-in/address)
constexpr int OB  = 64;      // out-partial banks
constexpr int NR  = 8;       // dst ranges (one per XCD)
constexpr int CAP = 96;      // node bucket capacity: 96 ushort = 3 lines
constexpr int RSPAN = N / NR;          // 2500 nodes per range
constexpr int PB   = 625;    // partition blocks
constexpr int PE   = 1024;   // edges per partition block (PB*PE == E)
constexpr int WCAP = 80;     // per (wave,range) LDS capacity (mean 32, 9 sigma)
constexpr int PCAP = 320;    // per (block,range) global capacity = 4*WCAP, 20 lines
constexpr int CNTW = 5008;   // cnt words, padded for 64B alignment (NOT zeroed)
// fused bin||node geometry
constexpr int BCHUNK     = (PB + 3) / 4;        // 157 bundle-chunks per range
constexpr int BIN_BLOCKS = NR * BCHUNK;         // 1256 (r = blockIdx & 7)
constexpr int NODE_BLOCKS = N * 32 / 256;       // 2500
// zeroed prefix: deg + statsA + statsB + opart (+pad)
constexpr int ZWORDS = N + 2 * SB * 64 + OB * 3 + 16;
// alignment audit: deg 80000B + statsA 4096 + statsB 4096 + opart 768 +
// pad 64 = 89024 B == 0 mod 64; cnt 20032 B -> 109056 == 0 mod 64;
// bufG 6.4MB, slot 3.84MB, msg 1.28MB all 64B-multiples -> every gather
// target buffer stays line-aligned (R13 lesson).
// R15 lesson: NO device-scope __threadfence / last-block patterns in wide
// grids on gfx950 (non-coherent XCD L2s make fences ~serialize the grid);
// a kernel boundary is the cheap global barrier.

__device__ __forceinline__ float bf_lo(unsigned m) {
    return __uint_as_float(m << 16);
}
__device__ __forceinline__ float bf_hi(unsigned m) {
    return __uint_as_float(m & 0xffff0000u);
}

// ---------------------------------------------------------------------------
// 0) zero deg + statsA + statsB + opart (contiguous at ws start)
__global__ void k_zero(int* __restrict__ p) {
    int i = blockIdx.x * 256 + threadIdx.x;
    if (i < ZWORDS) p[i] = 0;
}

// ---------------------------------------------------------------------------
// 1) phase-1 radix partition + fused layer-0 column stats (R14-proven).
__global__ __launch_bounds__(256) void k_part(
    const int* __restrict__ src, const int* __restrict__ dst,
    unsigned* __restrict__ bufG, int* __restrict__ cnt,
    const float* __restrict__ x, float* __restrict__ statsA) {
    __shared__ unsigned bufL[4][NR][WCAP];
    __shared__ int cW[4][NR];
    __shared__ int base[4][NR];
    __shared__ float sred[64];
    int tid = threadIdx.x, w = tid >> 6;
    if (tid < 32) cW[tid >> 3][tid & 7] = 0;
    __syncthreads();
    int e = blockIdx.x * PE + tid * 4;
    int4 d4 = *(const int4*)(dst + e);
    int4 s4 = *(const int4*)(src + e);
    int dd[4] = {d4.x, d4.y, d4.z, d4.w};
    int ss[4] = {s4.x, s4.y, s4.z, s4.w};
#pragma unroll
    for (int k = 0; k < 4; ++k) {
        int d = dd[k];
        int r = d / RSPAN;                // magic-mul divide
        int dl = d - r * RSPAN;
        int pos = atomicAdd(&cW[w][r], 1);
        if (pos < WCAP)
            bufL[w][r][pos] = ((unsigned)dl << 15) | (unsigned)ss[k];
    }
    __syncthreads();
    if (tid < 32) {                       // thread (w,r): flush base offsets
        int ww = tid >> 3, rr = tid & 7;
        int b = 0;
        for (int u = 0; u < ww; ++u) b += min(cW[u][rr], WCAP);
        base[ww][rr] = b;
        if (ww == 3) cnt[rr * PB + blockIdx.x] = b + min(cW[3][rr], WCAP);
    }
    __syncthreads();
    int lane = tid & 63;
    for (int r = 0; r < NR; ++r) {
        int c = min(cW[w][r], WCAP);
        unsigned* dp = bufG + ((size_t)r * PB + blockIdx.x) * PCAP + base[w][r];
        for (int i = lane; i < c; i += 64) dp[i] = bufL[w][r][i];
    }
    // fused layer-0 column stats (float4; PB*256 == N*T/4 exactly)
    int gid = blockIdx.x * 256 + tid;
    int GS  = gridDim.x * 256;
    const float4* x4 = (const float4*)x;
    float s0 = 0.f, s1 = 0.f, s2 = 0.f, s3 = 0.f;
    float q0 = 0.f, q1 = 0.f, q2 = 0.f, q3 = 0.f;
    for (int i = gid; i < N * T / 4; i += GS) {
        float4 v = x4[i];
        s0 += v.x; q0 += v.x * v.x;
        s1 += v.y; q1 += v.y * v.y;
        s2 += v.z; q2 += v.z * v.z;
        s3 += v.w; q3 += v.w * v.w;
    }
    int c4 = (tid & 7) * 4;
#pragma unroll
    for (int ofs = 8; ofs < 64; ofs <<= 1) {
        s0 += __shfl_xor(s0, ofs); q0 += __shfl_xor(q0, ofs);
        s1 += __shfl_xor(s1, ofs); q1 += __shfl_xor(q1, ofs);
        s2 += __shfl_xor(s2, ofs); q2 += __shfl_xor(q2, ofs);
        s3 += __shfl_xor(s3, ofs); q3 += __shfl_xor(q3, ofs);
    }
    if (tid < 64) sred[tid] = 0.f;
    __syncthreads();
    if ((tid & 63) < 8) {
        atomicAdd(&sred[c4 + 0], s0); atomicAdd(&sred[32 + c4 + 0], q0);
        atomicAdd(&sred[c4 + 1], s1); atomicAdd(&sred[32 + c4 + 1], q1);
        atomicAdd(&sred[c4 + 2], s2); atomicAdd(&sred[32 + c4 + 2], q2);
        atomicAdd(&sred[c4 + 3], s3); atomicAdd(&sred[32 + c4 + 3], q3);
    }
    __syncthreads();
    if (tid < 64)
        atomicAdd(&statsA[(blockIdx.x & (SB - 1)) * 64 + tid], sred[tid]);
}

// ---------------------------------------------------------------------------
// 2) FUSED bin2 || node0 (R15-introduced, not implicated in regression).
//    Blocks [0, BIN_BLOCKS): scatter packed edges into node buckets.
//    Blocks [BIN_BLOCKS, +NODE_BLOCKS): layer-0 norm+conv+max.
__global__ __launch_bounds__(256) void k_binnode(
    const unsigned* __restrict__ bufG, const int* __restrict__ cnt,
    int* __restrict__ deg, unsigned short* __restrict__ slot,
    const float* __restrict__ xin, const float* __restrict__ grep,
    const float* __restrict__ Wl, const float* __restrict__ bl,
    const float* __restrict__ al, const float* __restrict__ sl,
    const float* __restrict__ shl,
    float* __restrict__ xhat, unsigned short* __restrict__ msg) {
    int tid = threadIdx.x;
    if (blockIdx.x < BIN_BLOCKS) {
        int r = blockIdx.x & (NR - 1);
        int b = (blockIdx.x >> 3) * 4 + (tid >> 6);   // bundle b in range r
        if (b >= PB) return;
        int lane = tid & 63;
        int c = cnt[r * PB + b];
        const unsigned* bp = bufG + ((size_t)r * PB + b) * PCAP;
        int lo = r * RSPAN;
        for (int i = lane; i < c; i += 64) {
            unsigned pk = bp[i];
            int d = lo + (int)(pk >> 15);
            int s = (int)(pk & 32767u);
            int p = atomicAdd(&deg[d], 1);
            if (p < CAP) slot[d * CAP + p] = (unsigned short)s;
        }
        return;
    }
    // ---- node path ----
    int gid = (blockIdx.x - BIN_BLOCKS) * 256 + tid;
    int t = gid & 31;
    int row = gid >> 5;
    if (row >= N) return;

    float Sx = 0.f, Sx2 = 0.f;
#pragma unroll
    for (int b = 0; b < SB; ++b) {
        Sx  += grep[b * 64 + t];
        Sx2 += grep[b * 64 + 32 + t];
    }
    float mu   = Sx * (1.0f / (float)N);
    float am   = al[t] * mu;
    float nrm2 = Sx2 - 2.f * am * Sx + (float)N * am * am;
    float g    = sl[t] * sqrtf((float)N) * rsqrtf(nrm2);
    float h    = shl[t] - am * g;

    float v = g * xin[row * T + t] + h;
    xhat[row * T + t] = v;
    float vm2 = __shfl(v, t - 2, 32); if (t < 2)  vm2 = 0.f;
    float vm1 = __shfl(v, t - 1, 32); if (t < 1)  vm1 = 0.f;
    float vp1 = __shfl(v, t + 1, 32); if (t > 30) vp1 = 0.f;
    float vp2 = __shfl(v, t + 2, 32); if (t > 29) vp2 = 0.f;
    float m = -3.0e38f;
#pragma unroll
    for (int c = 0; c < C; ++c) {
        float a = bl[c] + Wl[c * K + 0] * vm2 + Wl[c * K + 1] * vm1
                        + Wl[c * K + 2] * v   + Wl[c * K + 3] * vp1
                        + Wl[c * K + 4] * vp2;
        m = fmaxf(m, a);
    }
    __hip_bfloat16 mb = __float2bfloat16(m);
    msg[row * T + t] = *(unsigned short*)&mb;
}

// ---------------------------------------------------------------------------
// 3) per-node GraphNorm affine + Conv1d + channel max (layer 1, standalone).
__global__ __launch_bounds__(256) void k_node(
    const float* __restrict__ xin, const float* __restrict__ grep,
    const float* __restrict__ Wl, const float* __restrict__ bl,
    const float* __restrict__ al, const float* __restrict__ sl,
    const float* __restrict__ shl,
    float* __restrict__ xhat, unsigned short* __restrict__ msg) {
    int gid = blockIdx.x * 256 + threadIdx.x;
    int t = gid & 31;
    int row = gid >> 5;
    if (row >= N) return;

    float Sx = 0.f, Sx2 = 0.f;
#pragma unroll
    for (int b = 0; b < SB; ++b) {
        Sx  += grep[b * 64 + t];
        Sx2 += grep[b * 64 + 32 + t];
    }
    float mu   = Sx * (1.0f / (float)N);
    float am   = al[t] * mu;
    float nrm2 = Sx2 - 2.f * am * Sx + (float)N * am * am;
    float g    = sl[t] * sqrtf((float)N) * rsqrtf(nrm2);
    float h    = shl[t] - am * g;

    float v = g * xin[row * T + t] + h;
    xhat[row * T + t] = v;
    float vm2 = __shfl(v, t - 2, 32); if (t < 2)  vm2 = 0.f;
    float vm1 = __shfl(v, t - 1, 32); if (t < 1)  vm1 = 0.f;
    float vp1 = __shfl(v, t + 1, 32); if (t > 30) vp1 = 0.f;
    float vp2 = __shfl(v, t + 2, 32); if (t > 29) vp2 = 0.f;
    float m = -3.0e38f;
#pragma unroll
    for (int c = 0; c < C; ++c) {
        float a = bl[c] + Wl[c * K + 0] * vm2 + Wl[c * K + 1] * vm1
                        + Wl[c * K + 2] * v   + Wl[c * K + 3] * vp1
                        + Wl[c * K + 4] * vp2;
        m = fmaxf(m, a);
    }
    __hip_bfloat16 mb = __float2bfloat16(m);
    msg[row * T + t] = *(unsigned short*)&mb;
}

// ---------------------------------------------------------------------------
// gather core (R12-proven): one wave per node; lane = g*16 + c; group g walks
// edges stride-4, 4-deep unroll -> 16 independent 64B rows in flight; lane
// covers columns (2c,2c+1) via one uint (2x bf16). fp32 accumulate.
__device__ __forceinline__ void gather_core(
    const int* __restrict__ deg, const unsigned short* __restrict__ slot,
    const unsigned* __restrict__ msgp, const float* __restrict__ xhat,
    int n, int c, int g, float* v0out, float* v1out) {
    int dg  = deg[n];
    int cnt = dg < CAP ? dg : CAP;
    const unsigned short* sl = slot + n * CAP;
    float a0 = 0.f, a1 = 0.f;
    int i = g;
    for (; i + 12 < cnt; i += 16) {
        int s0 = sl[i], s1 = sl[i + 4], s2 = sl[i + 8], s3 = sl[i + 12];
        unsigned m0 = msgp[s0 * 16 + c];
        unsigned m1 = msgp[s1 * 16 + c];
        unsigned m2 = msgp[s2 * 16 + c];
        unsigned m3 = msgp[s3 * 16 + c];
        a0 += bf_lo(m0); a1 += bf_hi(m0);
        a0 += bf_lo(m1); a1 += bf_hi(m1);
        a0 += bf_lo(m2); a1 += bf_hi(m2);
        a0 += bf_lo(m3); a1 += bf_hi(m3);
    }
    for (; i < cnt; i += 4) {
        unsigned m = msgp[(int)sl[i] * 16 + c];
        a0 += bf_lo(m); a1 += bf_hi(m);
    }
    a0 += __shfl_xor(a0, 16); a0 += __shfl_xor(a0, 32);
    a1 += __shfl_xor(a1, 16); a1 += __shfl_xor(a1, 32);
    float r = 1.0f / fmaxf((float)dg, 1.0f);
    float2 xh = ((const float2*)(xhat + n * T))[c];
    *v0out = fmaxf(0.5f * (xh.x + a0 * r), 0.f);
    *v1out = fmaxf(0.5f * (xh.y + a1 * r), 0.f);
}

// ---------------------------------------------------------------------------
// 4a) gather layer-0: epilogue -> x1 + banked next-layer stats.
__global__ __launch_bounds__(256) void k_gather0(
    const int* __restrict__ deg, const unsigned short* __restrict__ slot,
    const unsigned* __restrict__ msgp, const float* __restrict__ xhat,
    float* __restrict__ xout, float* __restrict__ statsB) {
    __shared__ float sred[64];
    int tid  = threadIdx.x;
    int gid  = blockIdx.x * 256 + tid;
    int lane = tid & 63;
    int g = lane >> 4, c = lane & 15;
    int n = gid >> 6;

    float v0 = 0.f, v1 = 0.f;
    bool valid = (n < N);
    if (valid) {
        gather_core(deg, slot, msgp, xhat, n, c, g, &v0, &v1);
        if (g == 0) {
            float2 w; w.x = v0; w.y = v1;
            ((float2*)(xout + n * T))[c] = w;
        }
    }
    if (tid < 64) sred[tid] = 0.f;
    __syncthreads();
    if (valid && g == 0) {
        atomicAdd(&sred[2 * c],          v0);
        atomicAdd(&sred[2 * c + 1],      v1);
        atomicAdd(&sred[32 + 2 * c],     v0 * v0);
        atomicAdd(&sred[32 + 2 * c + 1], v1 * v1);
    }
    __syncthreads();
    if (tid < 64)
        atomicAdd(&statsB[(blockIdx.x & (SB - 1)) * 64 + tid], sred[tid]);
}

// ---------------------------------------------------------------------------
// 4b) gather layer-1: epilogue -> banked Wout partials (R14-proven; no fence).
__global__ __launch_bounds__(256) void k_gather1(
    const int* __restrict__ deg, const unsigned short* __restrict__ slot,
    const unsigned* __restrict__ msgp, const float* __restrict__ xhat,
    const float* __restrict__ Wout, float* __restrict__ opart) {
    __shared__ float sred[3];
    int tid  = threadIdx.x;
    int gid  = blockIdx.x * 256 + tid;
    int lane = tid & 63;
    int g = lane >> 4, c = lane & 15;
    int n = gid >> 6;

    float v0 = 0.f, v1 = 0.f;
    bool valid = (n < N);
    if (valid) gather_core(deg, slot, msgp, xhat, n, c, g, &v0, &v1);

    float s = v0 + v1;
    s += __shfl_xor(s, 1); s += __shfl_xor(s, 2);
    s += __shfl_xor(s, 4); s += __shfl_xor(s, 8);
    float pa0 = 0.f, pa1 = 0.f, pa2 = 0.f;
    if (valid && lane == 0) {
        pa0 = Wout[n] * s;
        pa1 = Wout[N + n] * s;
        pa2 = Wout[2 * N + n] * s;
    }
    if (tid < 3) sred[tid] = 0.f;
    __syncthreads();
    if (lane == 0) {
        atomicAdd(&sred[0], pa0);
        atomicAdd(&sred[1], pa1);
        atomicAdd(&sred[2], pa2);
    }
    __syncthreads();
    if (tid < 3)
        atomicAdd(&opart[(blockIdx.x & (OB - 1)) * 3 + tid], sred[tid]);
}

// ---------------------------------------------------------------------------
// 5) final: out[j] = bout[j] + sum over banks
__global__ void k_finout(const float* __restrict__ opart,
                         const float* __restrict__ bout,
                         float* __restrict__ out) {
    int j = threadIdx.x;
    if (j < 3) {
        float s = bout[j];
        for (int b = 0; b < OB; ++b) s += opart[b * 3 + j];
        out[j] = s;
    }
}

// ---------------------------------------------------------------------------
extern "C" void kernel_launch(void* const* d_in, const int* in_sizes, int n_in,
                              void* d_out, int out_size, void* d_ws, size_t ws_size,
                              hipStream_t stream) {
    const float* x     = (const float*)d_in[0];
    const float* convW = (const float*)d_in[1];
    const float* convb = (const float*)d_in[2];
    const float* alpha = (const float*)d_in[3];
    const float* scale = (const float*)d_in[4];
    const float* shift = (const float*)d_in[5];
    const float* Wout  = (const float*)d_in[6];
    const float* bout  = (const float*)d_in[7];
    const int*   ei    = (const int*)d_in[8];
    const int* src = ei;          // edge_index[0]
    const int* dst = ei + E;      // edge_index[1]

    // workspace (64B-aligned throughout; see audit comment at top)
    int*            deg    = (int*)d_ws;                  // N (bucket cursor)
    float*          statsA = (float*)(deg + N);           // SB*64
    float*          statsB = statsA + SB * 64;            // SB*64
    float*          opart  = statsB + SB * 64;            // OB*3
    int*            pad    = (int*)(opart + OB * 3);      // 16 (zeroed, unused)
    int*            cnt    = pad + 16;                    // CNTW (not zeroed)
    unsigned*       bufG   = (unsigned*)(cnt + CNTW);     // NR*PB*PCAP
    unsigned short* slot   = (unsigned short*)(bufG + (size_t)NR * PB * PCAP);
    unsigned short* msg    = slot + (size_t)N * CAP;      // N*T (bf16 bits)
    float*          xhat   = (float*)(msg + (size_t)N * T);
    float*          x1     = xhat + N * T;
    float*          out    = (float*)d_out;

    k_zero<<<(ZWORDS + 255) / 256, 256, 0, stream>>>(deg);

    k_part<<<PB, 256, 0, stream>>>(src, dst, bufG, cnt, x, statsA);

    k_binnode<<<BIN_BLOCKS + NODE_BLOCKS, 256, 0, stream>>>(
        bufG, cnt, deg, slot,
        x, statsA, convW, convb, alpha, scale, shift, xhat, msg);

    k_gather0<<<(N * 64 + 255) / 256, 256, 0, stream>>>(
        deg, slot, (const unsigned*)msg, xhat, x1, statsB);

    k_node<<<NODE_BLOCKS, 256, 0, stream>>>(
        x1, statsB, convW + C * K, convb + C,
        alpha + T, scale + T, shift + T, xhat, msg);

    k_gather1<<<(N * 64 + 255) / 256, 256, 0, stream>>>(
        deg, slot, (const unsigned*)msg, xhat, Wout, opart);

    k_finout<<<1, 64, 0, stream>>>(opart, bout, out);
}

// Round 17
// 89.635 us; speedup vs baseline: 4.3876x; 1.0278x over previous
//
#include <hip/hip_runtime.h>
#include <hip/hip_bf16.h>

// Problem constants (match reference)
constexpr int N   = 20000;   // vertices
constexpr int T   = 32;      // temporal depth
constexpr int E   = 640000;  // edges
constexpr int C   = 10;      // conv out channels
constexpr int K   = 5;       // conv kernel size
constexpr int SB  = 16;      // stats replication banks (caps atomic fan-in/address)
constexpr int OB  = 64;      // out-partial banks
constexpr int NR  = 8;       // dst ranges (one per XCD)
constexpr int CAP = 96;      // node bucket capacity: 96 ushort = 3 lines
constexpr int RSPAN = N / NR;          // 2500 nodes per range
constexpr int PB   = 625;    // partition blocks
constexpr int PE   = 1024;   // edges per partition block (PB*PE == E)
constexpr int WCAP = 80;     // per (wave,range) LDS capacity (mean 32, 9 sigma)
constexpr int PCAP = 320;    // per (block,range) global capacity = 4*WCAP, 20 lines
constexpr int CNTW = 5008;   // cnt words, padded for 64B alignment (NOT zeroed)
// fused bin||node geometry
constexpr int BCHUNK     = (PB + 3) / 4;        // 157 bundle-chunks per range
constexpr int BIN_BLOCKS = NR * BCHUNK;         // 1256 (r = blockIdx & 7)
constexpr int NODE_BLOCKS = N * 32 / 256;       // 2500
// zeroed prefix now excludes deg (k_part zeroes it): statsA+statsB+opart+pad
constexpr int ZWORDS = 2 * SB * 64 + OB * 3 + 16;   // 2256
// alignment audit (layout unchanged from R16): deg 80000B + statsA 4096 +
// statsB 4096 + opart 768 + pad 64 = 89024 B == 0 mod 64; cnt 20032 B ->
// 109056 == 0 mod 64; bufG/slot/msg 64B-multiples -> gather targets aligned.
// R15 lesson: NO device-scope __threadfence / last-block patterns in wide
// grids (non-coherent XCD L2s); kernel boundary = the cheap global barrier.

__device__ __forceinline__ float bf_lo(unsigned m) {
    return __uint_as_float(m << 16);
}
__device__ __forceinline__ float bf_hi(unsigned m) {
    return __uint_as_float(m & 0xffff0000u);
}

// ---------------------------------------------------------------------------
// 0) zero statsA + statsB + opart (deg is zeroed inside k_part)
__global__ void k_zero(int* __restrict__ p) {
    int i = blockIdx.x * 256 + threadIdx.x;
    if (i < ZWORDS) p[i] = 0;
}

// ---------------------------------------------------------------------------
// 1) phase-1 radix partition + fused layer-0 column stats (R14-proven);
//    also zeroes deg (each block owns 32 ints; consumed next kernel).
__global__ __launch_bounds__(256) void k_part(
    const int* __restrict__ src, const int* __restrict__ dst,
    unsigned* __restrict__ bufG, int* __restrict__ cnt,
    const float* __restrict__ x, float* __restrict__ statsA,
    int* __restrict__ deg) {
    __shared__ unsigned bufL[4][NR][WCAP];
    __shared__ int cW[4][NR];
    __shared__ int base[4][NR];
    __shared__ float sred[64];
    int tid = threadIdx.x, w = tid >> 6;
    if (tid < 32) deg[blockIdx.x * 32 + tid] = 0;      // 625*32 == N exactly
    if (tid < 32) cW[tid >> 3][tid & 7] = 0;
    __syncthreads();
    int e = blockIdx.x * PE + tid * 4;
    int4 d4 = *(const int4*)(dst + e);
    int4 s4 = *(const int4*)(src + e);
    int dd[4] = {d4.x, d4.y, d4.z, d4.w};
    int ss[4] = {s4.x, s4.y, s4.z, s4.w};
#pragma unroll
    for (int k = 0; k < 4; ++k) {
        int d = dd[k];
        int r = d / RSPAN;                // magic-mul divide
        int dl = d - r * RSPAN;
        int pos = atomicAdd(&cW[w][r], 1);
        if (pos < WCAP)
            bufL[w][r][pos] = ((unsigned)dl << 15) | (unsigned)ss[k];
    }
    __syncthreads();
    if (tid < 32) {                       // thread (w,r): flush base offsets
        int ww = tid >> 3, rr = tid & 7;
        int b = 0;
        for (int u = 0; u < ww; ++u) b += min(cW[u][rr], WCAP);
        base[ww][rr] = b;
        if (ww == 3) cnt[rr * PB + blockIdx.x] = b + min(cW[3][rr], WCAP);
    }
    __syncthreads();
    int lane = tid & 63;
    for (int r = 0; r < NR; ++r) {
        int c = min(cW[w][r], WCAP);
        unsigned* dp = bufG + ((size_t)r * PB + blockIdx.x) * PCAP + base[w][r];
        for (int i = lane; i < c; i += 64) dp[i] = bufL[w][r][i];
    }
    // fused layer-0 column stats (float4; PB*256 == N*T/4 exactly)
    int gid = blockIdx.x * 256 + tid;
    int GS  = gridDim.x * 256;
    const float4* x4 = (const float4*)x;
    float s0 = 0.f, s1 = 0.f, s2 = 0.f, s3 = 0.f;
    float q0 = 0.f, q1 = 0.f, q2 = 0.f, q3 = 0.f;
    for (int i = gid; i < N * T / 4; i += GS) {
        float4 v = x4[i];
        s0 += v.x; q0 += v.x * v.x;
        s1 += v.y; q1 += v.y * v.y;
        s2 += v.z; q2 += v.z * v.z;
        s3 += v.w; q3 += v.w * v.w;
    }
    int c4 = (tid & 7) * 4;
#pragma unroll
    for (int ofs = 8; ofs < 64; ofs <<= 1) {
        s0 += __shfl_xor(s0, ofs); q0 += __shfl_xor(q0, ofs);
        s1 += __shfl_xor(s1, ofs); q1 += __shfl_xor(q1, ofs);
        s2 += __shfl_xor(s2, ofs); q2 += __shfl_xor(q2, ofs);
        s3 += __shfl_xor(s3, ofs); q3 += __shfl_xor(q3, ofs);
    }
    if (tid < 64) sred[tid] = 0.f;
    __syncthreads();
    if ((tid & 63) < 8) {
        atomicAdd(&sred[c4 + 0], s0); atomicAdd(&sred[32 + c4 + 0], q0);
        atomicAdd(&sred[c4 + 1], s1); atomicAdd(&sred[32 + c4 + 1], q1);
        atomicAdd(&sred[c4 + 2], s2); atomicAdd(&sred[32 + c4 + 2], q2);
        atomicAdd(&sred[c4 + 3], s3); atomicAdd(&sred[32 + c4 + 3], q3);
    }
    __syncthreads();
    if (tid < 64)
        atomicAdd(&statsA[(blockIdx.x & (SB - 1)) * 64 + tid], sred[tid]);
}

// ---------------------------------------------------------------------------
// 2) FUSED bin2 || node0 (R16-proven).
__global__ __launch_bounds__(256) void k_binnode(
    const unsigned* __restrict__ bufG, const int* __restrict__ cnt,
    int* __restrict__ deg, unsigned short* __restrict__ slot,
    const float* __restrict__ xin, const float* __restrict__ grep,
    const float* __restrict__ Wl, const float* __restrict__ bl,
    const float* __restrict__ al, const float* __restrict__ sl,
    const float* __restrict__ shl,
    float* __restrict__ xhat, unsigned short* __restrict__ msg) {
    int tid = threadIdx.x;
    if (blockIdx.x < BIN_BLOCKS) {
        int r = blockIdx.x & (NR - 1);
        int b = (blockIdx.x >> 3) * 4 + (tid >> 6);   // bundle b in range r
        if (b >= PB) return;
        int lane = tid & 63;
        int c = cnt[r * PB + b];
        const unsigned* bp = bufG + ((size_t)r * PB + b) * PCAP;
        int lo = r * RSPAN;
        for (int i = lane; i < c; i += 64) {
            unsigned pk = bp[i];
            int d = lo + (int)(pk >> 15);
            int s = (int)(pk & 32767u);
            int p = atomicAdd(&deg[d], 1);
            if (p < CAP) slot[d * CAP + p] = (unsigned short)s;
        }
        return;
    }
    // ---- node path ----
    int gid = (blockIdx.x - BIN_BLOCKS) * 256 + tid;
    int t = gid & 31;
    int row = gid >> 5;
    if (row >= N) return;

    float Sx = 0.f, Sx2 = 0.f;
#pragma unroll
    for (int b = 0; b < SB; ++b) {
        Sx  += grep[b * 64 + t];
        Sx2 += grep[b * 64 + 32 + t];
    }
    float mu   = Sx * (1.0f / (float)N);
    float am   = al[t] * mu;
    float nrm2 = Sx2 - 2.f * am * Sx + (float)N * am * am;
    float g    = sl[t] * sqrtf((float)N) * rsqrtf(nrm2);
    float h    = shl[t] - am * g;

    float v = g * xin[row * T + t] + h;
    xhat[row * T + t] = v;
    float vm2 = __shfl(v, t - 2, 32); if (t < 2)  vm2 = 0.f;
    float vm1 = __shfl(v, t - 1, 32); if (t < 1)  vm1 = 0.f;
    float vp1 = __shfl(v, t + 1, 32); if (t > 30) vp1 = 0.f;
    float vp2 = __shfl(v, t + 2, 32); if (t > 29) vp2 = 0.f;
    float m = -3.0e38f;
#pragma unroll
    for (int c = 0; c < C; ++c) {
        float a = bl[c] + Wl[c * K + 0] * vm2 + Wl[c * K + 1] * vm1
                        + Wl[c * K + 2] * v   + Wl[c * K + 3] * vp1
                        + Wl[c * K + 4] * vp2;
        m = fmaxf(m, a);
    }
    __hip_bfloat16 mb = __float2bfloat16(m);
    msg[row * T + t] = *(unsigned short*)&mb;
}

// ---------------------------------------------------------------------------
// 3) per-node GraphNorm affine + Conv1d + channel max (layer 1, standalone).
__global__ __launch_bounds__(256) void k_node(
    const float* __restrict__ xin, const float* __restrict__ grep,
    const float* __restrict__ Wl, const float* __restrict__ bl,
    const float* __restrict__ al, const float* __restrict__ sl,
    const float* __restrict__ shl,
    float* __restrict__ xhat, unsigned short* __restrict__ msg) {
    int gid = blockIdx.x * 256 + threadIdx.x;
    int t = gid & 31;
    int row = gid >> 5;
    if (row >= N) return;

    float Sx = 0.f, Sx2 = 0.f;
#pragma unroll
    for (int b = 0; b < SB; ++b) {
        Sx  += grep[b * 64 + t];
        Sx2 += grep[b * 64 + 32 + t];
    }
    float mu   = Sx * (1.0f / (float)N);
    float am   = al[t] * mu;
    float nrm2 = Sx2 - 2.f * am * Sx + (float)N * am * am;
    float g    = sl[t] * sqrtf((float)N) * rsqrtf(nrm2);
    float h    = shl[t] - am * g;

    float v = g * xin[row * T + t] + h;
    xhat[row * T + t] = v;
    float vm2 = __shfl(v, t - 2, 32); if (t < 2)  vm2 = 0.f;
    float vm1 = __shfl(v, t - 1, 32); if (t < 1)  vm1 = 0.f;
    float vp1 = __shfl(v, t + 1, 32); if (t > 30) vp1 = 0.f;
    float vp2 = __shfl(v, t + 2, 32); if (t > 29) vp2 = 0.f;
    float m = -3.0e38f;
#pragma unroll
    for (int c = 0; c < C; ++c) {
        float a = bl[c] + Wl[c * K + 0] * vm2 + Wl[c * K + 1] * vm1
                        + Wl[c * K + 2] * v   + Wl[c * K + 3] * vp1
                        + Wl[c * K + 4] * vp2;
        m = fmaxf(m, a);
    }
    __hip_bfloat16 mb = __float2bfloat16(m);
    msg[row * T + t] = *(unsigned short*)&mb;
}

// ---------------------------------------------------------------------------
// gather core (R12-proven): one wave per node; lane = g*16 + c; group g walks
// edges stride-4, 4-deep unroll -> 16 independent 64B rows in flight; lane
// covers columns (2c,2c+1) via one uint (2x bf16). fp32 accumulate.
__device__ __forceinline__ void gather_core(
    const int* __restrict__ deg, const unsigned short* __restrict__ slot,
    const unsigned* __restrict__ msgp, const float* __restrict__ xhat,
    int n, int c, int g, float* v0out, float* v1out) {
    int dg  = deg[n];
    int cnt = dg < CAP ? dg : CAP;
    const unsigned short* sl = slot + n * CAP;
    float a0 = 0.f, a1 = 0.f;
    int i = g;
    for (; i + 12 < cnt; i += 16) {
        int s0 = sl[i], s1 = sl[i + 4], s2 = sl[i + 8], s3 = sl[i + 12];
        unsigned m0 = msgp[s0 * 16 + c];
        unsigned m1 = msgp[s1 * 16 + c];
        unsigned m2 = msgp[s2 * 16 + c];
        unsigned m3 = msgp[s3 * 16 + c];
        a0 += bf_lo(m0); a1 += bf_hi(m0);
        a0 += bf_lo(m1); a1 += bf_hi(m1);
        a0 += bf_lo(m2); a1 += bf_hi(m2);
        a0 += bf_lo(m3); a1 += bf_hi(m3);
    }
    for (; i < cnt; i += 4) {
        unsigned m = msgp[(int)sl[i] * 16 + c];
        a0 += bf_lo(m); a1 += bf_hi(m);
    }
    a0 += __shfl_xor(a0, 16); a0 += __shfl_xor(a0, 32);
    a1 += __shfl_xor(a1, 16); a1 += __shfl_xor(a1, 32);
    float r = 1.0f / fmaxf((float)dg, 1.0f);
    float2 xh = ((const float2*)(xhat + n * T))[c];
    *v0out = fmaxf(0.5f * (xh.x + a0 * r), 0.f);
    *v1out = fmaxf(0.5f * (xh.y + a1 * r), 0.f);
}

// XCD-affinity node mapping for gathers: r = blockIdx&7 matches the range
// whose deg/slot lines were written by binnode blocks on the same XCD ->
// the dependent index-load head of each wave hits the local L2.
// grid = NR * (RSPAN/4) = 8 * 625 = 5000 blocks; wave w handles
// n = r*RSPAN + (blockIdx>>3)*4 + w  (exact cover, always < N).
__device__ __forceinline__ int gather_node(int blk, int wave) {
    int r = blk & (NR - 1);
    return r * RSPAN + (blk >> 3) * 4 + wave;
}

// ---------------------------------------------------------------------------
// 4a) gather layer-0: epilogue -> x1 + banked next-layer stats.
__global__ __launch_bounds__(256) void k_gather0(
    const int* __restrict__ deg, const unsigned short* __restrict__ slot,
    const unsigned* __restrict__ msgp, const float* __restrict__ xhat,
    float* __restrict__ xout, float* __restrict__ statsB) {
    __shared__ float sred[64];
    int tid  = threadIdx.x;
    int lane = tid & 63;
    int g = lane >> 4, c = lane & 15;
    int n = gather_node(blockIdx.x, tid >> 6);

    float v0, v1;
    gather_core(deg, slot, msgp, xhat, n, c, g, &v0, &v1);
    if (g == 0) {
        float2 w; w.x = v0; w.y = v1;
        ((float2*)(xout + n * T))[c] = w;
    }
    if (tid < 64) sred[tid] = 0.f;
    __syncthreads();
    if (g == 0) {
        atomicAdd(&sred[2 * c],          v0);
        atomicAdd(&sred[2 * c + 1],      v1);
        atomicAdd(&sred[32 + 2 * c],     v0 * v0);
        atomicAdd(&sred[32 + 2 * c + 1], v1 * v1);
    }
    __syncthreads();
    if (tid < 64)
        atomicAdd(&statsB[(blockIdx.x & (SB - 1)) * 64 + tid], sred[tid]);
}

// ---------------------------------------------------------------------------
// 4b) gather layer-1: epilogue -> banked Wout partials (no fence; R15 lesson).
__global__ __launch_bounds__(256) void k_gather1(
    const int* __restrict__ deg, const unsigned short* __restrict__ slot,
    const unsigned* __restrict__ msgp, const float* __restrict__ xhat,
    const float* __restrict__ Wout, float* __restrict__ opart) {
    __shared__ float sred[3];
    int tid  = threadIdx.x;
    int lane = tid & 63;
    int g = lane >> 4, c = lane & 15;
    int n = gather_node(blockIdx.x, tid >> 6);

    float v0, v1;
    gather_core(deg, slot, msgp, xhat, n, c, g, &v0, &v1);

    float s = v0 + v1;
    s += __shfl_xor(s, 1); s += __shfl_xor(s, 2);
    s += __shfl_xor(s, 4); s += __shfl_xor(s, 8);
    float pa0 = 0.f, pa1 = 0.f, pa2 = 0.f;
    if (lane == 0) {
        pa0 = Wout[n] * s;
        pa1 = Wout[N + n] * s;
        pa2 = Wout[2 * N + n] * s;
    }
    if (tid < 3) sred[tid] = 0.f;
    __syncthreads();
    if (lane == 0) {
        atomicAdd(&sred[0], pa0);
        atomicAdd(&sred[1], pa1);
        atomicAdd(&sred[2], pa2);
    }
    __syncthreads();
    if (tid < 3)
        atomicAdd(&opart[(blockIdx.x & (OB - 1)) * 3 + tid], sred[tid]);
}

// ---------------------------------------------------------------------------
// 5) final: out[j] = bout[j] + sum over banks
__global__ void k_finout(const float* __restrict__ opart,
                         const float* __restrict__ bout,
                         float* __restrict__ out) {
    int j = threadIdx.x;
    if (j < 3) {
        float s = bout[j];
        for (int b = 0; b < OB; ++b) s += opart[b * 3 + j];
        out[j] = s;
    }
}

// ---------------------------------------------------------------------------
extern "C" void kernel_launch(void* const* d_in, const int* in_sizes, int n_in,
                              void* d_out, int out_size, void* d_ws, size_t ws_size,
                              hipStream_t stream) {
    const float* x     = (const float*)d_in[0];
    const float* convW = (const float*)d_in[1];
    const float* convb = (const float*)d_in[2];
    const float* alpha = (const float*)d_in[3];
    const float* scale = (const float*)d_in[4];
    const float* shift = (const float*)d_in[5];
    const float* Wout  = (const float*)d_in[6];
    const float* bout  = (const float*)d_in[7];
    const int*   ei    = (const int*)d_in[8];
    const int* src = ei;          // edge_index[0]
    const int* dst = ei + E;      // edge_index[1]

    // workspace (64B-aligned throughout; see audit comment at top)
    int*            deg    = (int*)d_ws;                  // N (bucket cursor)
    float*          statsA = (float*)(deg + N);           // SB*64
    float*          statsB = statsA + SB * 64;            // SB*64
    float*          opart  = statsB + SB * 64;            // OB*3
    int*            pad    = (int*)(opart + OB * 3);      // 16
    int*            cnt    = pad + 16;                    // CNTW (not zeroed)
    unsigned*       bufG   = (unsigned*)(cnt + CNTW);     // NR*PB*PCAP
    unsigned short* slot   = (unsigned short*)(bufG + (size_t)NR * PB * PCAP);
    unsigned short* msg    = slot + (size_t)N * CAP;      // N*T (bf16 bits)
    float*          xhat   = (float*)(msg + (size_t)N * T);
    float*          x1     = xhat + N * T;
    float*          out    = (float*)d_out;

    k_zero<<<(ZWORDS + 255) / 256, 256, 0, stream>>>((int*)statsA);

    k_part<<<PB, 256, 0, stream>>>(src, dst, bufG, cnt, x, statsA, deg);

    k_binnode<<<BIN_BLOCKS + NODE_BLOCKS, 256, 0, stream>>>(
        bufG, cnt, deg, slot,
        x, statsA, convW, convb, alpha, scale, shift, xhat, msg);

    k_gather0<<<NR * (RSPAN / 4), 256, 0, stream>>>(
        deg, slot, (const unsigned*)msg, xhat, x1, statsB);

    k_node<<<NODE_BLOCKS, 256, 0, stream>>>(
        x1, statsB, convW + C * K, convb + C,
        alpha + T, scale + T, shift + T, xhat, msg);

    k_gather1<<<NR * (RSPAN / 4), 256, 0, stream>>>(
        deg, slot, (const unsigned*)msg, xhat, Wout, opart);

    k_finout<<<1, 64, 0, stream>>>(opart, bout, out);
}

// Round 18
// 89.266 us; speedup vs baseline: 4.4058x; 1.0041x over previous
//
#include <hip/hip_runtime.h>
#include <hip/hip_bf16.h>

// Problem constants (match reference)
constexpr int N   = 20000;   // vertices
constexpr int T   = 32;      // temporal depth
constexpr int E   = 640000;  // edges
constexpr int C   = 10;      // conv out channels
constexpr int K   = 5;       // conv kernel size
constexpr int SB  = 16;      // stats replication banks (caps atomic fan-in/address)
constexpr int OB  = 64;      // out-partial banks
constexpr int NR  = 8;       // dst ranges (one per XCD)
constexpr int CAP = 96;      // node bucket capacity: 96 ushort = 3 lines
constexpr int RSPAN = N / NR;          // 2500 nodes per range
constexpr int PB   = 625;    // partition blocks
constexpr int PE   = 1024;   // edges per partition block (PB*PE == E)
constexpr int WCAP = 80;     // per (wave,range) LDS capacity (mean 32, 9 sigma)
constexpr int PCAP = 320;    // per (block,range) global capacity = 4*WCAP, 20 lines
constexpr int CNTW = 5008;   // cnt words, padded for 64B alignment (NOT zeroed)
// fused bin||node geometry
constexpr int BCHUNK     = (PB + 3) / 4;        // 157 bundle-chunks per range
constexpr int BIN_BLOCKS = NR * BCHUNK;         // 1256 (r = blockIdx & 7)
constexpr int NODE_BLOCKS = N * 32 / 256;       // 2500
// zeroed prefix: statsA + statsB + opart (+pad); deg zeroed in k_part
constexpr int ZWORDS = 2 * SB * 64 + OB * 3 + 16;   // 2256
// alignment audit: deg 80000B + statsA 4096 + statsB 4096 + opart 768 +
// pad 64 = 89024 B == 0 mod 64; cnt 20032 -> 109056 == 0 mod 64; bufG 8MB,
// slot 3.84MB, msg 1.28MB, xhat 1.28MB, x1 1.28MB all 64B-multiples.
// R15 lesson: NO device-scope __threadfence / last-block patterns in wide
// grids (non-coherent XCD L2s); kernel boundary = the cheap global barrier.

__device__ __forceinline__ float bf_lo(unsigned m) {
    return __uint_as_float(m << 16);
}
__device__ __forceinline__ float bf_hi(unsigned m) {
    return __uint_as_float(m & 0xffff0000u);
}
__device__ __forceinline__ unsigned short f2bf(float f) {
    __hip_bfloat16 b = __float2bfloat16(f);
    return *(unsigned short*)&b;
}

// ---------------------------------------------------------------------------
// 0) zero statsA + statsB + opart (deg is zeroed inside k_part)
__global__ void k_zero(int* __restrict__ p) {
    int i = blockIdx.x * 256 + threadIdx.x;
    if (i < ZWORDS) p[i] = 0;
}

// ---------------------------------------------------------------------------
// 1) phase-1 radix partition + fused layer-0 column stats; zeroes deg.
__global__ __launch_bounds__(256) void k_part(
    const int* __restrict__ src, const int* __restrict__ dst,
    unsigned* __restrict__ bufG, int* __restrict__ cnt,
    const float* __restrict__ x, float* __restrict__ statsA,
    int* __restrict__ deg) {
    __shared__ unsigned bufL[4][NR][WCAP];
    __shared__ int cW[4][NR];
    __shared__ int base[4][NR];
    __shared__ float sred[64];
    int tid = threadIdx.x, w = tid >> 6;
    if (tid < 32) deg[blockIdx.x * 32 + tid] = 0;      // 625*32 == N exactly
    if (tid < 32) cW[tid >> 3][tid & 7] = 0;
    __syncthreads();
    int e = blockIdx.x * PE + tid * 4;
    int4 d4 = *(const int4*)(dst + e);
    int4 s4 = *(const int4*)(src + e);
    int dd[4] = {d4.x, d4.y, d4.z, d4.w};
    int ss[4] = {s4.x, s4.y, s4.z, s4.w};
#pragma unroll
    for (int k = 0; k < 4; ++k) {
        int d = dd[k];
        int r = d / RSPAN;                // magic-mul divide
        int dl = d - r * RSPAN;
        int pos = atomicAdd(&cW[w][r], 1);
        if (pos < WCAP)
            bufL[w][r][pos] = ((unsigned)dl << 15) | (unsigned)ss[k];
    }
    __syncthreads();
    if (tid < 32) {                       // thread (w,r): flush base offsets
        int ww = tid >> 3, rr = tid & 7;
        int b = 0;
        for (int u = 0; u < ww; ++u) b += min(cW[u][rr], WCAP);
        base[ww][rr] = b;
        if (ww == 3) cnt[rr * PB + blockIdx.x] = b + min(cW[3][rr], WCAP);
    }
    __syncthreads();
    int lane = tid & 63;
    for (int r = 0; r < NR; ++r) {
        int c = min(cW[w][r], WCAP);
        unsigned* dp = bufG + ((size_t)r * PB + blockIdx.x) * PCAP + base[w][r];
        for (int i = lane; i < c; i += 64) dp[i] = bufL[w][r][i];
    }
    // fused layer-0 column stats (float4; PB*256 == N*T/4 exactly)
    int gid = blockIdx.x * 256 + tid;
    int GS  = gridDim.x * 256;
    const float4* x4 = (const float4*)x;
    float s0 = 0.f, s1 = 0.f, s2 = 0.f, s3 = 0.f;
    float q0 = 0.f, q1 = 0.f, q2 = 0.f, q3 = 0.f;
    for (int i = gid; i < N * T / 4; i += GS) {
        float4 v = x4[i];
        s0 += v.x; q0 += v.x * v.x;
        s1 += v.y; q1 += v.y * v.y;
        s2 += v.z; q2 += v.z * v.z;
        s3 += v.w; q3 += v.w * v.w;
    }
    int c4 = (tid & 7) * 4;
#pragma unroll
    for (int ofs = 8; ofs < 64; ofs <<= 1) {
        s0 += __shfl_xor(s0, ofs); q0 += __shfl_xor(q0, ofs);
        s1 += __shfl_xor(s1, ofs); q1 += __shfl_xor(q1, ofs);
        s2 += __shfl_xor(s2, ofs); q2 += __shfl_xor(q2, ofs);
        s3 += __shfl_xor(s3, ofs); q3 += __shfl_xor(q3, ofs);
    }
    if (tid < 64) sred[tid] = 0.f;
    __syncthreads();
    if ((tid & 63) < 8) {
        atomicAdd(&sred[c4 + 0], s0); atomicAdd(&sred[32 + c4 + 0], q0);
        atomicAdd(&sred[c4 + 1], s1); atomicAdd(&sred[32 + c4 + 1], q1);
        atomicAdd(&sred[c4 + 2], s2); atomicAdd(&sred[32 + c4 + 2], q2);
        atomicAdd(&sred[c4 + 3], s3); atomicAdd(&sred[32 + c4 + 3], q3);
    }
    __syncthreads();
    if (tid < 64)
        atomicAdd(&statsA[(blockIdx.x & (SB - 1)) * 64 + tid], sred[tid]);
}

// ---------------------------------------------------------------------------
// shared node-path body: GraphNorm affine + conv + channel-max.
// IN_BF16: input rows are bf16 bits (layer 1); else fp32 (layer 0).
template <int IN_BF16, typename XT>
__device__ __forceinline__ void node_body(
    const XT* __restrict__ xin, const float* __restrict__ grep,
    const float* __restrict__ Wl, const float* __restrict__ bl,
    const float* __restrict__ al, const float* __restrict__ sl,
    const float* __restrict__ shl,
    unsigned short* __restrict__ xhat, unsigned short* __restrict__ msg,
    int gid) {
    int t = gid & 31;
    int row = gid >> 5;
    if (row >= N) return;

    float Sx = 0.f, Sx2 = 0.f;
#pragma unroll
    for (int b = 0; b < SB; ++b) {
        Sx  += grep[b * 64 + t];
        Sx2 += grep[b * 64 + 32 + t];
    }
    float mu   = Sx * (1.0f / (float)N);
    float am   = al[t] * mu;
    float nrm2 = Sx2 - 2.f * am * Sx + (float)N * am * am;
    float g    = sl[t] * sqrtf((float)N) * rsqrtf(nrm2);
    float h    = shl[t] - am * g;

    float xv;
    if (IN_BF16) {
        unsigned short u = *(const unsigned short*)&xin[row * T + t];
        xv = __uint_as_float((unsigned)u << 16);
    } else {
        xv = (float)xin[row * T + t];
    }
    float v = g * xv + h;
    xhat[row * T + t] = f2bf(v);
    float vm2 = __shfl(v, t - 2, 32); if (t < 2)  vm2 = 0.f;
    float vm1 = __shfl(v, t - 1, 32); if (t < 1)  vm1 = 0.f;
    float vp1 = __shfl(v, t + 1, 32); if (t > 30) vp1 = 0.f;
    float vp2 = __shfl(v, t + 2, 32); if (t > 29) vp2 = 0.f;
    float m = -3.0e38f;
#pragma unroll
    for (int c = 0; c < C; ++c) {
        float a = bl[c] + Wl[c * K + 0] * vm2 + Wl[c * K + 1] * vm1
                        + Wl[c * K + 2] * v   + Wl[c * K + 3] * vp1
                        + Wl[c * K + 4] * vp2;
        m = fmaxf(m, a);
    }
    msg[row * T + t] = f2bf(m);
}

// ---------------------------------------------------------------------------
// 2) FUSED bin2 || node0 (R16-proven).
__global__ __launch_bounds__(256) void k_binnode(
    const unsigned* __restrict__ bufG, const int* __restrict__ cnt,
    int* __restrict__ deg, unsigned short* __restrict__ slot,
    const float* __restrict__ xin, const float* __restrict__ grep,
    const float* __restrict__ Wl, const float* __restrict__ bl,
    const float* __restrict__ al, const float* __restrict__ sl,
    const float* __restrict__ shl,
    unsigned short* __restrict__ xhat, unsigned short* __restrict__ msg) {
    int tid = threadIdx.x;
    if (blockIdx.x < BIN_BLOCKS) {
        int r = blockIdx.x & (NR - 1);
        int b = (blockIdx.x >> 3) * 4 + (tid >> 6);   // bundle b in range r
        if (b >= PB) return;
        int lane = tid & 63;
        int c = cnt[r * PB + b];
        const unsigned* bp = bufG + ((size_t)r * PB + b) * PCAP;
        int lo = r * RSPAN;
        for (int i = lane; i < c; i += 64) {
            unsigned pk = bp[i];
            int d = lo + (int)(pk >> 15);
            int s = (int)(pk & 32767u);
            int p = atomicAdd(&deg[d], 1);
            if (p < CAP) slot[d * CAP + p] = (unsigned short)s;
        }
        return;
    }
    node_body<0>(xin, grep, Wl, bl, al, sl, shl, xhat, msg,
                 (blockIdx.x - BIN_BLOCKS) * 256 + tid);
}

// ---------------------------------------------------------------------------
// 3) layer-1 node: input x1 is bf16.
__global__ __launch_bounds__(256) void k_node(
    const unsigned short* __restrict__ xin, const float* __restrict__ grep,
    const float* __restrict__ Wl, const float* __restrict__ bl,
    const float* __restrict__ al, const float* __restrict__ sl,
    const float* __restrict__ shl,
    unsigned short* __restrict__ xhat, unsigned short* __restrict__ msg) {
    node_body<1>(xin, grep, Wl, bl, al, sl, shl, xhat, msg,
                 blockIdx.x * 256 + threadIdx.x);
}

// ---------------------------------------------------------------------------
// gather core (R12-proven layout, bf16 xhat): one wave per node; lane = g*16+c;
// group g walks edges stride-4, 4-deep unroll -> 16 independent 64B rows in
// flight; lane covers columns (2c,2c+1) via one uint (2x bf16). fp32 accum.
__device__ __forceinline__ void gather_core(
    const int* __restrict__ deg, const unsigned short* __restrict__ slot,
    const unsigned* __restrict__ msgp, const unsigned* __restrict__ xhatp,
    int n, int c, int g, float* v0out, float* v1out) {
    int dg  = deg[n];
    int cnt = dg < CAP ? dg : CAP;
    const unsigned short* sl = slot + n * CAP;
    float a0 = 0.f, a1 = 0.f;
    int i = g;
    for (; i + 12 < cnt; i += 16) {
        int s0 = sl[i], s1 = sl[i + 4], s2 = sl[i + 8], s3 = sl[i + 12];
        unsigned m0 = msgp[s0 * 16 + c];
        unsigned m1 = msgp[s1 * 16 + c];
        unsigned m2 = msgp[s2 * 16 + c];
        unsigned m3 = msgp[s3 * 16 + c];
        a0 += bf_lo(m0); a1 += bf_hi(m0);
        a0 += bf_lo(m1); a1 += bf_hi(m1);
        a0 += bf_lo(m2); a1 += bf_hi(m2);
        a0 += bf_lo(m3); a1 += bf_hi(m3);
    }
    for (; i < cnt; i += 4) {
        unsigned m = msgp[(int)sl[i] * 16 + c];
        a0 += bf_lo(m); a1 += bf_hi(m);
    }
    a0 += __shfl_xor(a0, 16); a0 += __shfl_xor(a0, 32);
    a1 += __shfl_xor(a1, 16); a1 += __shfl_xor(a1, 32);
    float r = 1.0f / fmaxf((float)dg, 1.0f);
    unsigned xh = xhatp[n * 16 + c];
    *v0out = fmaxf(0.5f * (bf_lo(xh) + a0 * r), 0.f);
    *v1out = fmaxf(0.5f * (bf_hi(xh) + a1 * r), 0.f);
}

// XCD-affinity node mapping (R17-proven): r = blockIdx&7 matches the range
// whose deg/slot lines were written by binnode blocks on the same XCD.
__device__ __forceinline__ int gather_node(int blk, int wave) {
    int r = blk & (NR - 1);
    return r * RSPAN + (blk >> 3) * 4 + wave;
}

// ---------------------------------------------------------------------------
// 4a) gather layer-0: epilogue -> x1 (bf16) + banked next-layer stats.
__global__ __launch_bounds__(256) void k_gather0(
    const int* __restrict__ deg, const unsigned short* __restrict__ slot,
    const unsigned* __restrict__ msgp, const unsigned* __restrict__ xhatp,
    unsigned* __restrict__ xout, float* __restrict__ statsB) {
    __shared__ float sred[64];
    int tid  = threadIdx.x;
    int lane = tid & 63;
    int g = lane >> 4, c = lane & 15;
    int n = gather_node(blockIdx.x, tid >> 6);

    float v0, v1;
    gather_core(deg, slot, msgp, xhatp, n, c, g, &v0, &v1);
    if (g == 0) {
        xout[n * 16 + c] = (unsigned)f2bf(v0) | ((unsigned)f2bf(v1) << 16);
    }
    if (tid < 64) sred[tid] = 0.f;
    __syncthreads();
    if (g == 0) {
        atomicAdd(&sred[2 * c],          v0);
        atomicAdd(&sred[2 * c + 1],      v1);
        atomicAdd(&sred[32 + 2 * c],     v0 * v0);
        atomicAdd(&sred[32 + 2 * c + 1], v1 * v1);
    }
    __syncthreads();
    if (tid < 64)
        atomicAdd(&statsB[(blockIdx.x & (SB - 1)) * 64 + tid], sred[tid]);
}

// ---------------------------------------------------------------------------
// 4b) gather layer-1: epilogue -> banked Wout partials (no fence; R15 lesson).
__global__ __launch_bounds__(256) void k_gather1(
    const int* __restrict__ deg, const unsigned short* __restrict__ slot,
    const unsigned* __restrict__ msgp, const unsigned* __restrict__ xhatp,
    const float* __restrict__ Wout, float* __restrict__ opart) {
    __shared__ float sred[3];
    int tid  = threadIdx.x;
    int lane = tid & 63;
    int g = lane >> 4, c = lane & 15;
    int n = gather_node(blockIdx.x, tid >> 6);

    float v0, v1;
    gather_core(deg, slot, msgp, xhatp, n, c, g, &v0, &v1);

    float s = v0 + v1;
    s += __shfl_xor(s, 1); s += __shfl_xor(s, 2);
    s += __shfl_xor(s, 4); s += __shfl_xor(s, 8);
    float pa0 = 0.f, pa1 = 0.f, pa2 = 0.f;
    if (lane == 0) {
        pa0 = Wout[n] * s;
        pa1 = Wout[N + n] * s;
        pa2 = Wout[2 * N + n] * s;
    }
    if (tid < 3) sred[tid] = 0.f;
    __syncthreads();
    if (lane == 0) {
        atomicAdd(&sred[0], pa0);
        atomicAdd(&sred[1], pa1);
        atomicAdd(&sred[2], pa2);
    }
    __syncthreads();
    if (tid < 3)
        atomicAdd(&opart[(blockIdx.x & (OB - 1)) * 3 + tid], sred[tid]);
}

// ---------------------------------------------------------------------------
// 5) final: out[j] = bout[j] + sum over banks
__global__ void k_finout(const float* __restrict__ opart,
                         const float* __restrict__ bout,
                         float* __restrict__ out) {
    int j = threadIdx.x;
    if (j < 3) {
        float s = bout[j];
        for (int b = 0; b < OB; ++b) s += opart[b * 3 + j];
        out[j] = s;
    }
}

// ---------------------------------------------------------------------------
extern "C" void kernel_launch(void* const* d_in, const int* in_sizes, int n_in,
                              void* d_out, int out_size, void* d_ws, size_t ws_size,
                              hipStream_t stream) {
    const float* x     = (const float*)d_in[0];
    const float* convW = (const float*)d_in[1];
    const float* convb = (const float*)d_in[2];
    const float* alpha = (const float*)d_in[3];
    const float* scale = (const float*)d_in[4];
    const float* shift = (const float*)d_in[5];
    const float* Wout  = (const float*)d_in[6];
    const float* bout  = (const float*)d_in[7];
    const int*   ei    = (const int*)d_in[8];
    const int* src = ei;          // edge_index[0]
    const int* dst = ei + E;      // edge_index[1]

    // workspace (64B-aligned throughout; see audit comment at top)
    int*            deg    = (int*)d_ws;                  // N (bucket cursor)
    float*          statsA = (float*)(deg + N);           // SB*64
    float*          statsB = statsA + SB * 64;            // SB*64
    float*          opart  = statsB + SB * 64;            // OB*3
    int*            pad    = (int*)(opart + OB * 3);      // 16
    int*            cnt    = pad + 16;                    // CNTW (not zeroed)
    unsigned*       bufG   = (unsigned*)(cnt + CNTW);     // NR*PB*PCAP
    unsigned short* slot   = (unsigned short*)(bufG + (size_t)NR * PB * PCAP);
    unsigned short* msg    = slot + (size_t)N * CAP;      // N*T (bf16 bits)
    unsigned short* xhat   = msg + (size_t)N * T;         // N*T (bf16 bits)
    unsigned short* x1     = xhat + (size_t)N * T;        // N*T (bf16 bits)
    float*          out    = (float*)d_out;

    k_zero<<<(ZWORDS + 255) / 256, 256, 0, stream>>>((int*)statsA);

    k_part<<<PB, 256, 0, stream>>>(src, dst, bufG, cnt, x, statsA, deg);

    k_binnode<<<BIN_BLOCKS + NODE_BLOCKS, 256, 0, stream>>>(
        bufG, cnt, deg, slot,
        x, statsA, convW, convb, alpha, scale, shift, xhat, msg);

    k_gather0<<<NR * (RSPAN / 4), 256, 0, stream>>>(
        deg, slot, (const unsigned*)msg, (const unsigned*)xhat,
        (unsigned*)x1, statsB);

    k_node<<<NODE_BLOCKS, 256, 0, stream>>>(
        x1, statsB, convW + C * K, convb + C,
        alpha + T, scale + T, shift + T, xhat, msg);

    k_gather1<<<NR * (RSPAN / 4), 256, 0, stream>>>(
        deg, slot, (const unsigned*)msg, (const unsigned*)xhat, Wout, opart);

    k_finout<<<1, 64, 0, stream>>>(opart, bout, out);
}

// Round 19
// 86.704 us; speedup vs baseline: 4.5359x; 1.0295x over previous
//
#include <hip/hip_runtime.h>
#include <hip/hip_bf16.h>

// Problem constants (match reference)
constexpr int N   = 20000;   // vertices
constexpr int T   = 32;      // temporal depth
constexpr int E   = 640000;  // edges
constexpr int C   = 10;      // conv out channels
constexpr int K   = 5;       // conv kernel size
constexpr int SB  = 16;      // stats replication banks (caps atomic fan-in/address)
constexpr int OB  = 64;      // out-partial banks
constexpr int NR  = 8;       // dst ranges (one per XCD)
constexpr int CAP = 96;      // node bucket capacity: 96 ushort = 3 lines
constexpr int RSPAN = N / NR;          // 2500 nodes per range
constexpr int PB   = 625;    // partition blocks
constexpr int PE   = 1024;   // edges per partition block (PB*PE == E)
constexpr int WCAP = 80;     // per (wave,range) LDS capacity (mean 32, 9 sigma)
constexpr int PCAP = 320;    // per (block,range) global capacity = 4*WCAP, 20 lines
constexpr int CNTW = 5008;   // cnt words, padded for 64B alignment (NOT zeroed)
// fused bin||node geometry
constexpr int BCHUNK     = (PB + 3) / 4;        // 157 bundle-chunks per range
constexpr int BIN_BLOCKS = NR * BCHUNK;         // 1256 (r = blockIdx & 7)
constexpr int NODE_BLOCKS = N * 32 / 256;       // 2500
// zeroed prefix: statsA + statsB + opart (+pad); deg zeroed in k_part
constexpr int ZWORDS = 2 * SB * 64 + OB * 3 + 16;   // 2256
// alignment audit: deg 80000B + statsA 4096 + statsB 4096 + opart 768 +
// pad 64 = 89024 B == 0 mod 64; cnt 20032 -> 109056 == 0 mod 64; bufG 8MB,
// slot 3.84MB, msg/xhat/x1 1.28MB each, all 64B-multiples.
// R15 lesson: NO device-scope __threadfence / last-block patterns in wide
// grids (non-coherent XCD L2s); kernel boundary = the cheap global barrier.

__device__ __forceinline__ float bf_lo(unsigned m) {
    return __uint_as_float(m << 16);
}
__device__ __forceinline__ float bf_hi(unsigned m) {
    return __uint_as_float(m & 0xffff0000u);
}
__device__ __forceinline__ unsigned short f2bf(float f) {
    __hip_bfloat16 b = __float2bfloat16(f);
    return *(unsigned short*)&b;
}

// ---------------------------------------------------------------------------
// 0) zero statsA + statsB + opart (deg is zeroed inside k_part)
__global__ void k_zero(int* __restrict__ p) {
    int i = blockIdx.x * 256 + threadIdx.x;
    if (i < ZWORDS) p[i] = 0;
}

// ---------------------------------------------------------------------------
// 1) phase-1 radix partition + fused layer-0 column stats; zeroes deg.
__global__ __launch_bounds__(256) void k_part(
    const int* __restrict__ src, const int* __restrict__ dst,
    unsigned* __restrict__ bufG, int* __restrict__ cnt,
    const float* __restrict__ x, float* __restrict__ statsA,
    int* __restrict__ deg) {
    __shared__ unsigned bufL[4][NR][WCAP];
    __shared__ int cW[4][NR];
    __shared__ int base[4][NR];
    __shared__ float sred[64];
    int tid = threadIdx.x, w = tid >> 6;
    if (tid < 32) deg[blockIdx.x * 32 + tid] = 0;      // 625*32 == N exactly
    if (tid < 32) cW[tid >> 3][tid & 7] = 0;
    __syncthreads();
    int e = blockIdx.x * PE + tid * 4;
    int4 d4 = *(const int4*)(dst + e);
    int4 s4 = *(const int4*)(src + e);
    int dd[4] = {d4.x, d4.y, d4.z, d4.w};
    int ss[4] = {s4.x, s4.y, s4.z, s4.w};
#pragma unroll
    for (int k = 0; k < 4; ++k) {
        int d = dd[k];
        int r = d / RSPAN;                // magic-mul divide
        int dl = d - r * RSPAN;
        int pos = atomicAdd(&cW[w][r], 1);
        if (pos < WCAP)
            bufL[w][r][pos] = ((unsigned)dl << 15) | (unsigned)ss[k];
    }
    __syncthreads();
    if (tid < 32) {                       // thread (w,r): flush base offsets
        int ww = tid >> 3, rr = tid & 7;
        int b = 0;
        for (int u = 0; u < ww; ++u) b += min(cW[u][rr], WCAP);
        base[ww][rr] = b;
        if (ww == 3) cnt[rr * PB + blockIdx.x] = b + min(cW[3][rr], WCAP);
    }
    __syncthreads();
    int lane = tid & 63;
    for (int r = 0; r < NR; ++r) {
        int c = min(cW[w][r], WCAP);
        unsigned* dp = bufG + ((size_t)r * PB + blockIdx.x) * PCAP + base[w][r];
        for (int i = lane; i < c; i += 64) dp[i] = bufL[w][r][i];
    }
    // fused layer-0 column stats (float4; PB*256 == N*T/4 exactly)
    int gid = blockIdx.x * 256 + tid;
    int GS  = gridDim.x * 256;
    const float4* x4 = (const float4*)x;
    float s0 = 0.f, s1 = 0.f, s2 = 0.f, s3 = 0.f;
    float q0 = 0.f, q1 = 0.f, q2 = 0.f, q3 = 0.f;
    for (int i = gid; i < N * T / 4; i += GS) {
        float4 v = x4[i];
        s0 += v.x; q0 += v.x * v.x;
        s1 += v.y; q1 += v.y * v.y;
        s2 += v.z; q2 += v.z * v.z;
        s3 += v.w; q3 += v.w * v.w;
    }
    int c4 = (tid & 7) * 4;
#pragma unroll
    for (int ofs = 8; ofs < 64; ofs <<= 1) {
        s0 += __shfl_xor(s0, ofs); q0 += __shfl_xor(q0, ofs);
        s1 += __shfl_xor(s1, ofs); q1 += __shfl_xor(q1, ofs);
        s2 += __shfl_xor(s2, ofs); q2 += __shfl_xor(q2, ofs);
        s3 += __shfl_xor(s3, ofs); q3 += __shfl_xor(q3, ofs);
    }
    if (tid < 64) sred[tid] = 0.f;
    __syncthreads();
    if ((tid & 63) < 8) {
        atomicAdd(&sred[c4 + 0], s0); atomicAdd(&sred[32 + c4 + 0], q0);
        atomicAdd(&sred[c4 + 1], s1); atomicAdd(&sred[32 + c4 + 1], q1);
        atomicAdd(&sred[c4 + 2], s2); atomicAdd(&sred[32 + c4 + 2], q2);
        atomicAdd(&sred[c4 + 3], s3); atomicAdd(&sred[32 + c4 + 3], q3);
    }
    __syncthreads();
    if (tid < 64)
        atomicAdd(&statsA[(blockIdx.x & (SB - 1)) * 64 + tid], sred[tid]);
}

// ---------------------------------------------------------------------------
// shared node-path body: GraphNorm affine + conv + channel-max.
template <int IN_BF16, typename XT>
__device__ __forceinline__ void node_body(
    const XT* __restrict__ xin, const float* __restrict__ grep,
    const float* __restrict__ Wl, const float* __restrict__ bl,
    const float* __restrict__ al, const float* __restrict__ sl,
    const float* __restrict__ shl,
    unsigned short* __restrict__ xhat, unsigned short* __restrict__ msg,
    int gid) {
    int t = gid & 31;
    int row = gid >> 5;
    if (row >= N) return;

    float Sx = 0.f, Sx2 = 0.f;
#pragma unroll
    for (int b = 0; b < SB; ++b) {
        Sx  += grep[b * 64 + t];
        Sx2 += grep[b * 64 + 32 + t];
    }
    float mu   = Sx * (1.0f / (float)N);
    float am   = al[t] * mu;
    float nrm2 = Sx2 - 2.f * am * Sx + (float)N * am * am;
    float g    = sl[t] * sqrtf((float)N) * rsqrtf(nrm2);
    float h    = shl[t] - am * g;

    float xv;
    if (IN_BF16) {
        unsigned short u = *(const unsigned short*)&xin[row * T + t];
        xv = __uint_as_float((unsigned)u << 16);
    } else {
        xv = (float)xin[row * T + t];
    }
    float v = g * xv + h;
    xhat[row * T + t] = f2bf(v);
    float vm2 = __shfl(v, t - 2, 32); if (t < 2)  vm2 = 0.f;
    float vm1 = __shfl(v, t - 1, 32); if (t < 1)  vm1 = 0.f;
    float vp1 = __shfl(v, t + 1, 32); if (t > 30) vp1 = 0.f;
    float vp2 = __shfl(v, t + 2, 32); if (t > 29) vp2 = 0.f;
    float m = -3.0e38f;
#pragma unroll
    for (int c = 0; c < C; ++c) {
        float a = bl[c] + Wl[c * K + 0] * vm2 + Wl[c * K + 1] * vm1
                        + Wl[c * K + 2] * v   + Wl[c * K + 3] * vp1
                        + Wl[c * K + 4] * vp2;
        m = fmaxf(m, a);
    }
    msg[row * T + t] = f2bf(m);
}

// ---------------------------------------------------------------------------
// 2) FUSED bin2 || node0 (R16-proven).
__global__ __launch_bounds__(256) void k_binnode(
    const unsigned* __restrict__ bufG, const int* __restrict__ cnt,
    int* __restrict__ deg, unsigned short* __restrict__ slot,
    const float* __restrict__ xin, const float* __restrict__ grep,
    const float* __restrict__ Wl, const float* __restrict__ bl,
    const float* __restrict__ al, const float* __restrict__ sl,
    const float* __restrict__ shl,
    unsigned short* __restrict__ xhat, unsigned short* __restrict__ msg) {
    int tid = threadIdx.x;
    if (blockIdx.x < BIN_BLOCKS) {
        int r = blockIdx.x & (NR - 1);
        int b = (blockIdx.x >> 3) * 4 + (tid >> 6);   // bundle b in range r
        if (b >= PB) return;
        int lane = tid & 63;
        int c = cnt[r * PB + b];
        const unsigned* bp = bufG + ((size_t)r * PB + b) * PCAP;
        int lo = r * RSPAN;
        for (int i = lane; i < c; i += 64) {
            unsigned pk = bp[i];
            int d = lo + (int)(pk >> 15);
            int s = (int)(pk & 32767u);
            int p = atomicAdd(&deg[d], 1);
            if (p < CAP) slot[d * CAP + p] = (unsigned short)s;
        }
        return;
    }
    node_body<0>(xin, grep, Wl, bl, al, sl, shl, xhat, msg,
                 (blockIdx.x - BIN_BLOCKS) * 256 + tid);
}

// ---------------------------------------------------------------------------
// 3) layer-1 node: input x1 is bf16.
__global__ __launch_bounds__(256) void k_node(
    const unsigned short* __restrict__ xin, const float* __restrict__ grep,
    const float* __restrict__ Wl, const float* __restrict__ bl,
    const float* __restrict__ al, const float* __restrict__ sl,
    const float* __restrict__ shl,
    unsigned short* __restrict__ xhat, unsigned short* __restrict__ msg) {
    node_body<1>(xin, grep, Wl, bl, al, sl, shl, xhat, msg,
                 blockIdx.x * 256 + threadIdx.x);
}

// ---------------------------------------------------------------------------
// gather core, uint2 variant: one wave per node; lane = g*8 + c; 8 edge-groups
// walk the bucket stride-8, 2-deep unroll -> 16 independent 64B rows in
// flight; each lane covers columns (4c..4c+3) via one uint2 (4x bf16).
// Halves load-instruction count per edge vs the 16-lane uint shape
// (transactions identical) -> isolates issue-bound vs request-bound.
__device__ __forceinline__ void gather_core(
    const int* __restrict__ deg, const unsigned short* __restrict__ slot,
    const uint2* __restrict__ msgp2, const uint2* __restrict__ xhatp2,
    int n, int c, int g, float* v) {
    int dg  = deg[n];
    int cnt = dg < CAP ? dg : CAP;
    const unsigned short* sl = slot + n * CAP;
    float a0 = 0.f, a1 = 0.f, a2 = 0.f, a3 = 0.f;
    int i = g;
    for (; i + 8 < cnt; i += 16) {
        int s0 = sl[i], s1 = sl[i + 8];
        uint2 m0 = msgp2[s0 * 8 + c];
        uint2 m1 = msgp2[s1 * 8 + c];
        a0 += bf_lo(m0.x); a1 += bf_hi(m0.x);
        a2 += bf_lo(m0.y); a3 += bf_hi(m0.y);
        a0 += bf_lo(m1.x); a1 += bf_hi(m1.x);
        a2 += bf_lo(m1.y); a3 += bf_hi(m1.y);
    }
    for (; i < cnt; i += 8) {
        uint2 m = msgp2[(int)sl[i] * 8 + c];
        a0 += bf_lo(m.x); a1 += bf_hi(m.x);
        a2 += bf_lo(m.y); a3 += bf_hi(m.y);
    }
    // fold the 8 edge-groups (lane bits [3:5]; columns stay lane-local)
#pragma unroll
    for (int ofs = 8; ofs < 64; ofs <<= 1) {
        a0 += __shfl_xor(a0, ofs);
        a1 += __shfl_xor(a1, ofs);
        a2 += __shfl_xor(a2, ofs);
        a3 += __shfl_xor(a3, ofs);
    }
    float r = 1.0f / fmaxf((float)dg, 1.0f);
    uint2 xh = xhatp2[n * 8 + c];
    v[0] = fmaxf(0.5f * (bf_lo(xh.x) + a0 * r), 0.f);
    v[1] = fmaxf(0.5f * (bf_hi(xh.x) + a1 * r), 0.f);
    v[2] = fmaxf(0.5f * (bf_lo(xh.y) + a2 * r), 0.f);
    v[3] = fmaxf(0.5f * (bf_hi(xh.y) + a3 * r), 0.f);
}

// XCD-affinity node mapping (R17-proven): r = blockIdx&7 matches the range
// whose deg/slot lines were written by binnode blocks on the same XCD.
__device__ __forceinline__ int gather_node(int blk, int wave) {
    int r = blk & (NR - 1);
    return r * RSPAN + (blk >> 3) * 4 + wave;
}

// ---------------------------------------------------------------------------
// 4a) gather layer-0: epilogue -> x1 (bf16) + banked next-layer stats.
__global__ __launch_bounds__(256) void k_gather0(
    const int* __restrict__ deg, const unsigned short* __restrict__ slot,
    const uint2* __restrict__ msgp2, const uint2* __restrict__ xhatp2,
    uint2* __restrict__ xout2, float* __restrict__ statsB) {
    __shared__ float sred[64];
    int tid  = threadIdx.x;
    int lane = tid & 63;
    int g = lane >> 3, c = lane & 7;
    int n = gather_node(blockIdx.x, tid >> 6);

    float v[4];
    gather_core(deg, slot, msgp2, xhatp2, n, c, g, v);
    if (g == 0) {
        uint2 w;
        w.x = (unsigned)f2bf(v[0]) | ((unsigned)f2bf(v[1]) << 16);
        w.y = (unsigned)f2bf(v[2]) | ((unsigned)f2bf(v[3]) << 16);
        xout2[n * 8 + c] = w;
    }
    if (tid < 64) sred[tid] = 0.f;
    __syncthreads();
    if (g == 0) {
#pragma unroll
        for (int k = 0; k < 4; ++k) {
            atomicAdd(&sred[4 * c + k],      v[k]);
            atomicAdd(&sred[32 + 4 * c + k], v[k] * v[k]);
        }
    }
    __syncthreads();
    if (tid < 64)
        atomicAdd(&statsB[(blockIdx.x & (SB - 1)) * 64 + tid], sred[tid]);
}

// ---------------------------------------------------------------------------
// 4b) gather layer-1: epilogue -> banked Wout partials (no fence; R15 lesson).
__global__ __launch_bounds__(256) void k_gather1(
    const int* __restrict__ deg, const unsigned short* __restrict__ slot,
    const uint2* __restrict__ msgp2, const uint2* __restrict__ xhatp2,
    const float* __restrict__ Wout, float* __restrict__ opart) {
    __shared__ float sred[3];
    int tid  = threadIdx.x;
    int lane = tid & 63;
    int g = lane >> 3, c = lane & 7;
    int n = gather_node(blockIdx.x, tid >> 6);

    float v[4];
    gather_core(deg, slot, msgp2, xhatp2, n, c, g, v);

    float s = v[0] + v[1] + v[2] + v[3];   // fold 8 c-values (lane bits [0:2])
    s += __shfl_xor(s, 1); s += __shfl_xor(s, 2); s += __shfl_xor(s, 4);
    float pa0 = 0.f, pa1 = 0.f, pa2 = 0.f;
    if (lane == 0) {                        // s = full rowsum of node n
        pa0 = Wout[n] * s;
        pa1 = Wout[N + n] * s;
        pa2 = Wout[2 * N + n] * s;
    }
    if (tid < 3) sred[tid] = 0.f;
    __syncthreads();
    if (lane == 0) {
        atomicAdd(&sred[0], pa0);
        atomicAdd(&sred[1], pa1);
        atomicAdd(&sred[2], pa2);
    }
    __syncthreads();
    if (tid < 3)
        atomicAdd(&opart[(blockIdx.x & (OB - 1)) * 3 + tid], sred[tid]);
}

// ---------------------------------------------------------------------------
// 5) final: out[j] = bout[j] + sum over banks
__global__ void k_finout(const float* __restrict__ opart,
                         const float* __restrict__ bout,
                         float* __restrict__ out) {
    int j = threadIdx.x;
    if (j < 3) {
        float s = bout[j];
        for (int b = 0; b < OB; ++b) s += opart[b * 3 + j];
        out[j] = s;
    }
}

// ---------------------------------------------------------------------------
extern "C" void kernel_launch(void* const* d_in, const int* in_sizes, int n_in,
                              void* d_out, int out_size, void* d_ws, size_t ws_size,
                              hipStream_t stream) {
    const float* x     = (const float*)d_in[0];
    const float* convW = (const float*)d_in[1];
    const float* convb = (const float*)d_in[2];
    const float* alpha = (const float*)d_in[3];
    const float* scale = (const float*)d_in[4];
    const float* shift = (const float*)d_in[5];
    const float* Wout  = (const float*)d_in[6];
    const float* bout  = (const float*)d_in[7];
    const int*   ei    = (const int*)d_in[8];
    const int* src = ei;          // edge_index[0]
    const int* dst = ei + E;      // edge_index[1]

    // workspace (64B-aligned throughout; see audit comment at top)
    int*            deg    = (int*)d_ws;                  // N (bucket cursor)
    float*          statsA = (float*)(deg + N);           // SB*64
    float*          statsB = statsA + SB * 64;            // SB*64
    float*          opart  = statsB + SB * 64;            // OB*3
    int*            pad    = (int*)(opart + OB * 3);      // 16
    int*            cnt    = pad + 16;                    // CNTW (not zeroed)
    unsigned*       bufG   = (unsigned*)(cnt + CNTW);     // NR*PB*PCAP
    unsigned short* slot   = (unsigned short*)(bufG + (size_t)NR * PB * PCAP);
    unsigned short* msg    = slot + (size_t)N * CAP;      // N*T (bf16 bits)
    unsigned short* xhat   = msg + (size_t)N * T;         // N*T (bf16 bits)
    unsigned short* x1     = xhat + (size_t)N * T;        // N*T (bf16 bits)
    float*          out    = (float*)d_out;

    k_zero<<<(ZWORDS + 255) / 256, 256, 0, stream>>>((int*)statsA);

    k_part<<<PB, 256, 0, stream>>>(src, dst, bufG, cnt, x, statsA, deg);

    k_binnode<<<BIN_BLOCKS + NODE_BLOCKS, 256, 0, stream>>>(
        bufG, cnt, deg, slot,
        x, statsA, convW, convb, alpha, scale, shift, xhat, msg);

    k_gather0<<<NR * (RSPAN / 4), 256, 0, stream>>>(
        deg, slot, (const uint2*)msg, (const uint2*)xhat,
        (uint2*)x1, statsB);

    k_node<<<NODE_BLOCKS, 256, 0, stream>>>(
        x1, statsB, convW + C * K, convb + C,
        alpha + T, scale + T, shift + T, xhat, msg);

    k_gather1<<<NR * (RSPAN / 4), 256, 0, stream>>>(
        deg, slot, (const uint2*)msg, (const uint2*)xhat, Wout, opart);

    k_finout<<<1, 64, 0, stream>>>(opart, bout, out);
}